// Round 14
// baseline (204.506 us; speedup 1.0000x reference)
//
#include <hip/hip_runtime.h>
#include <hip/hip_bf16.h>

// FlashMultiHeadAttention: x -> QKV proj -> causal GQA flash attn -> out proj
// B=2 N=2048 E=2048 HQ=32 HKV=8 D=64 G=4. All compute in bf16 MFMA, fp32 accum.

#define B_   2
#define N_   2048
#define E_   2048
#define HQ_  32
#define HKV_ 8
#define D_   64
#define BN_  (B_*N_)   // 4096 total rows

typedef __attribute__((ext_vector_type(8))) short bf16x8;
typedef __attribute__((ext_vector_type(4))) float f32x4;

#define MFMA16(a,b,c) __builtin_amdgcn_mfma_f32_16x16x32_bf16(a,b,c,0,0,0)

__device__ inline unsigned short f2bf(float f) {
  unsigned u = __builtin_bit_cast(unsigned, f);
  u += 0x7FFFu + ((u >> 16) & 1u);   // RNE
  return (unsigned short)(u >> 16);
}

__device__ inline void gload_lds16(const void* g, void* l) {
  __builtin_amdgcn_global_load_lds(
      (const __attribute__((address_space(1))) void*)g,
      (__attribute__((address_space(3))) void*)l, 16, 0, 0);
}

// ---------------- fused cast fp32 -> bf16 for x,Wq,Wk,Wv,Wo ----------------
__global__ void cast_all(const float* __restrict__ x,  const float* __restrict__ wq,
                         const float* __restrict__ wk, const float* __restrict__ wv,
                         const float* __restrict__ wo, unsigned short* __restrict__ dst) {
  const int c0 = 2097152;            // x      (8388608 elems /4)
  const int c1 = c0 + 1048576;       // Wq
  const int c2 = c1 + 262144;        // Wk
  const int c3 = c2 + 262144;        // Wv
  const int c4 = c3 + 1048576;       // Wo
  int i = blockIdx.x * blockDim.x + threadIdx.x;
  const int stride = gridDim.x * blockDim.x;
  for (; i < c4; i += stride) {
    const float* src; int off;
    if      (i < c0) { src = x;  off = i; }
    else if (i < c1) { src = wq; off = i - c0; }
    else if (i < c2) { src = wk; off = i - c1; }
    else if (i < c3) { src = wv; off = i - c2; }
    else             { src = wo; off = i - c3; }
    float4 f = reinterpret_cast<const float4*>(src)[off];
    ushort4 u;
    u.x = f2bf(f.x); u.y = f2bf(f.y); u.z = f2bf(f.z); u.w = f2bf(f.w);
    reinterpret_cast<ushort4*>(dst)[i] = u;
  }
}

// ---------------- fused QKV projection GEMM: 256x256, thin 2-barrier schedule -----
// BM=BN=256, BK=64. 512 thr = 8 waves (2M x 4N), per-wave 128x64 (acc[8][4]).
// LDS 128KB: As/Bs[2 buf][2 half][128*64] (v12 layout, 0 bank conflicts).
// Per tile t: stage BOTH halves of t+1 into buf^1 (8 wave-loads) -> vmcnt(8)
// (tile-t loads landed; t+1's 8 stay in flight ACROSS barriers - T4) ->
// s_barrier -> full-tile compute (2 ks x [4 B-frags + 2 mq x (4 A-frags +
// setprio'd 16 MFMA)]) -> s_barrier. 2 barriers/tile, no main-loop drain.
// Grid 192 = 8 XCD groups x 24 (bm pair per XCD).
__global__ __launch_bounds__(512) void gemm_qkv(
    const unsigned short* __restrict__ A,
    const unsigned short* __restrict__ Wq, const unsigned short* __restrict__ Wk,
    const unsigned short* __restrict__ Wv,
    const float* __restrict__ bq, const float* __restrict__ bk, const float* __restrict__ bv,
    unsigned short* __restrict__ Qo, unsigned short* __restrict__ Ko,
    unsigned short* __restrict__ Vto)
{
  __shared__ __align__(16) unsigned short As[2][2][8192];  // [buf][half][128*64]
  __shared__ __align__(16) unsigned short Bs[2][2][8192];
  const int tid  = threadIdx.x;
  const int w    = tid >> 6;
  const int lane = tid & 63;
  const int g    = blockIdx.x & 7;       // XCD slot
  const int s    = blockIdx.x >> 3;      // 0..23
  const int bm   = g*2 + (s >= 12);
  const int bn   = (s >= 12) ? (s - 12) : s;
  const int m0   = bm << 8;
  const int n0v  = bn << 8;              // virtual col in [Q|K|V] = 3072
  const int K    = E_;

  const unsigned short* W; const float* bias; int wn0, seg;
  if      (n0v < 2048) { W = Wq; bias = bq; wn0 = n0v;        seg = 0; }
  else if (n0v < 2560) { W = Wk; bias = bk; wn0 = n0v - 2048; seg = 1; }
  else                 { W = Wv; bias = bv; wn0 = n0v - 2560; seg = 2; }

  const int mr   = w >> 2;               // wave m-half (0/1): rows mr*128..+128
  const int nc   = w & 3;                // wave n-col: cols nc*64..+64
  const int cl   = lane & 15;
  const int kgrp = lane >> 4;
  const int rl   = kgrp << 2;
  const int li   = lane >> 3;            // staging row-in-group 0..7
  const int lx   = lane & 7;             // staging chunk 0..7

  // staging bases: half h, wave rows w*16+q*8+li; global chunk = lx^li
  const unsigned gsw = ((unsigned)(lx ^ li)) << 3;   // elems
  const unsigned short* gA[2]; const unsigned short* gB[2];
  #pragma unroll
  for (int h = 0; h < 2; ++h) {
    gA[h] = A + (size_t)(m0  + h*128 + w*16 + li) * K + gsw;
    gB[h] = W + (size_t)(wn0 + h*128 + w*16 + li) * K + gsw;
  }
  const unsigned ldso = (unsigned)(w*16)*64u + (unsigned)lane*8u;  // elems in half
  const unsigned rsw  = (unsigned)(cl & 7);

  f32x4 acc[8][4] = {};
  const int nt = K >> 6;   // 32

  auto STAGE_P = [&](int kt, int buf, int h) {   // 4 wave-loads: 2 A + 2 B
    const int ko = kt << 6;
    #pragma unroll
    for (int q = 0; q < 2; ++q)
      gload_lds16(gA[h] + (size_t)(q*8)*K + ko, &As[buf][h][ldso + q*512]);
    #pragma unroll
    for (int q = 0; q < 2; ++q)
      gload_lds16(gB[h] + (size_t)(q*8)*K + ko, &Bs[buf][h][ldso + q*512]);
  };

  STAGE_P(0, 0, 0); STAGE_P(0, 0, 1);
  int p = 0;

  for (int t = 0; t < nt; ++t) {
    if (t + 1 < nt) {
      STAGE_P(t + 1, p ^ 1, 0);
      STAGE_P(t + 1, p ^ 1, 1);
      asm volatile("s_waitcnt vmcnt(8)" ::: "memory");   // tile-t landed
    } else {
      asm volatile("s_waitcnt vmcnt(0)" ::: "memory");
    }
    __builtin_amdgcn_s_barrier();
    const unsigned short* Ah = As[p][mr];
    const unsigned short* Bh = Bs[p][nc >> 1];
    #pragma unroll
    for (int ks = 0; ks < 2; ++ks) {
      bf16x8 bfr[4];
      #pragma unroll
      for (int jj = 0; jj < 4; ++jj) {
        const unsigned row = (unsigned)((nc & 1)*64 + jj*16 + cl);
        bfr[jj] = *reinterpret_cast<const bf16x8*>(
            &Bh[row*64u + ((((unsigned)(ks*4 + kgrp)) ^ rsw) << 3)]);
      }
      #pragma unroll
      for (int mq = 0; mq < 2; ++mq) {
        bf16x8 af[4];
        #pragma unroll
        for (int z = 0; z < 4; ++z) {
          const unsigned row = (unsigned)(mq*64 + z*16 + cl);
          af[z] = *reinterpret_cast<const bf16x8*>(
              &Ah[row*64u + ((((unsigned)(ks*4 + kgrp)) ^ rsw) << 3)]);
        }
        __builtin_amdgcn_s_setprio(1);
        #pragma unroll
        for (int z = 0; z < 4; ++z)
          #pragma unroll
          for (int jj = 0; jj < 4; ++jj)
            acc[mq*4 + z][jj] = MFMA16(af[z], bfr[jj], acc[mq*4 + z][jj]);
        __builtin_amdgcn_s_setprio(0);
      }
    }
    __builtin_amdgcn_s_barrier();   // reads of buf p consumed -> safe to restage
    p ^= 1;
  }

  // epilogue
  #pragma unroll
  for (int mi = 0; mi < 8; ++mi) {
    const int rowb = m0 + mr*128 + (mi >> 2)*64 + (mi & 3)*16 + rl;
    #pragma unroll
    for (int jj = 0; jj < 4; ++jj) {
      const int col = wn0 + nc*64 + jj*16 + cl;
      const float bj = bias[col];
      if (seg == 0) {
        #pragma unroll
        for (int r = 0; r < 4; ++r)
          Qo[(size_t)(rowb + r) * 2048 + col] = f2bf(acc[mi][jj][r] + bj);
      } else if (seg == 1) {
        #pragma unroll
        for (int r = 0; r < 4; ++r)
          Ko[(size_t)(rowb + r) * 512 + col] = f2bf(acc[mi][jj][r] + bj);
      } else {
        ushort4 u;
        u.x = f2bf(acc[mi][jj][0] + bj);
        u.y = f2bf(acc[mi][jj][1] + bj);
        u.z = f2bf(acc[mi][jj][2] + bj);
        u.w = f2bf(acc[mi][jj][3] + bj);
        *reinterpret_cast<ushort4*>(&Vto[(size_t)col * 4096 + rowb]) = u;
      }
    }
  }
}

// ---------------- out-proj GEMM: 256x128 tile, grid 256 = exact 1/CU fill ---------
// BM=256, BN=128, BK=64. 512 thr = 8 waves (4M x 2N), per-wave 64x64 (acc[4][4]).
// LDS 96KB: As[2][256*64] (32KB) + Bs[2][128*64] (16KB). Thin schedule: per tile
// {STAGE(t+1)->buf^1 (6 wave-loads: 4 A + 2 B) -> vmcnt(6) -> barrier ->
// 16 ds_read_b128 + 32 MFMA (setprio) -> barrier}. Same verified XOR swizzle.
// Grid 256 = 8 XCD groups x 32 (bm pair per XCD x all 16 bn).
__global__ __launch_bounds__(512) void gemm_out(
    const unsigned short* __restrict__ A, const unsigned short* __restrict__ W,
    const float* __restrict__ bias, float* __restrict__ C)
{
  __shared__ __align__(16) unsigned short As[2][16384];   // [buf][256*64]
  __shared__ __align__(16) unsigned short Bs[2][8192];    // [buf][128*64]
  const int tid  = threadIdx.x;
  const int w    = tid >> 6;
  const int lane = tid & 63;
  const int g    = blockIdx.x & 7;       // XCD slot
  const int s    = blockIdx.x >> 3;      // 0..31
  const int bm   = g*2 + (s >> 4);       // 0..15
  const int bn   = s & 15;               // 0..15
  const int m0   = bm << 8, n0 = bn << 7;
  const int K    = E_;
  const int wr   = (w >> 1) << 6;        // 0,64,128,192
  const int wc   = (w & 1) << 6;         // 0/64
  const int cl   = lane & 15;
  const int kgrp = lane >> 4;
  const int rl   = kgrp << 2;
  const int li   = lane >> 3;
  const int lx   = lane & 7;

  const unsigned schunk = ((unsigned)(lx ^ li)) << 3;   // elems
  const unsigned short* gA = A + (size_t)(m0 + w*32 + li) * K + schunk;
  const unsigned short* gB = W + (size_t)(n0 + w*16 + li) * K + schunk;
  const unsigned lA0 = (unsigned)(w*32)*64u + (unsigned)lane*8u;   // elems
  const unsigned lB0 = (unsigned)(w*16)*64u + (unsigned)lane*8u;

  unsigned rAo[4][2], rBo[4][2];
  #pragma unroll
  for (int z = 0; z < 4; ++z)
    #pragma unroll
    for (int ks = 0; ks < 2; ++ks) {
      const unsigned ch = (((unsigned)(ks*4 + kgrp)) ^ (unsigned)(cl & 7)) << 3;
      rAo[z][ks] = (unsigned)(wr + z*16 + cl)*64u + ch;
      rBo[z][ks] = (unsigned)(wc + z*16 + cl)*64u + ch;
    }

  f32x4 acc[4][4] = {};
  const int nt = K >> 6;   // 32

  auto STAGE = [&](int kt, int buf) {   // 6 wave-loads: 4 A (32 rows) + 2 B (16 rows)
    const int ko = kt << 6;
    #pragma unroll
    for (int q = 0; q < 4; ++q)
      gload_lds16(gA + (size_t)(q*8)*K + ko, &As[buf][lA0 + q*512]);
    #pragma unroll
    for (int q = 0; q < 2; ++q)
      gload_lds16(gB + (size_t)(q*8)*K + ko, &Bs[buf][lB0 + q*512]);
  };

  STAGE(0, 0);
  int p = 0;

  for (int t = 0; t < nt; ++t) {
    if (t + 1 < nt) {
      STAGE(t + 1, p ^ 1);
      asm volatile("s_waitcnt vmcnt(6)" ::: "memory");   // tile-t landed
    } else {
      asm volatile("s_waitcnt vmcnt(0)" ::: "memory");
    }
    __builtin_amdgcn_s_barrier();
    #pragma unroll
    for (int ks = 0; ks < 2; ++ks) {
      bf16x8 af[4], bfr[4];
      #pragma unroll
      for (int z = 0; z < 4; ++z)
        af[z] = *reinterpret_cast<const bf16x8*>(&As[p][rAo[z][ks]]);
      #pragma unroll
      for (int jj = 0; jj < 4; ++jj)
        bfr[jj] = *reinterpret_cast<const bf16x8*>(&Bs[p][rBo[jj][ks]]);
      __builtin_amdgcn_s_setprio(1);
      #pragma unroll
      for (int z = 0; z < 4; ++z)
        #pragma unroll
        for (int jj = 0; jj < 4; ++jj)
          acc[z][jj] = MFMA16(af[z], bfr[jj], acc[z][jj]);
      __builtin_amdgcn_s_setprio(0);
    }
    __builtin_amdgcn_s_barrier();
    p ^= 1;
  }

  #pragma unroll
  for (int jj = 0; jj < 4; ++jj) {
    const int col = n0 + wc + jj*16 + cl;
    const float bj = bias[col];
    #pragma unroll
    for (int z = 0; z < 4; ++z) {
      const int row = m0 + wr + z*16 + rl;
      #pragma unroll
      for (int r = 0; r < 4; ++r)
        C[(size_t)(row + r) * E_ + col] = acc[z][jj][r] + bj;
    }
  }
}

// ---------------- causal GQA flash attention (v8: LDS-staged shared K/V) ----------
// grid (16, 32): x = bh = b*8+h, y = pair j. Block = 4 waves = the 4 query heads
// sharing (b,h)'s K/V. All waves handle the SAME balanced 32-row strip pair
// (j, 63-j) -> identical nt -> lockstep barriers. Per kv tile (64 kv): K tile and
// V^T tile (8KB each) staged into double-buffered LDS by 16 coalesced
// global_load_lds, stage-ahead of compute. Both-sides XOR chunk swizzle.
// Compute engine: S^T = mfma(K,Q), lane-local softmax, P via swizzled per-wave
// LDS, O^T = mfma(V^T,P), l via ones-MFMA.
__global__ __launch_bounds__(256, 2) void attn_kernel(
    const unsigned short* __restrict__ Q, const unsigned short* __restrict__ K,
    const unsigned short* __restrict__ Vt, unsigned short* __restrict__ O)
{
  __shared__ __align__(16) unsigned short Kbuf[2][4096];   // [64 kv][64 d] swizzled
  __shared__ __align__(16) unsigned short Vbuf[2][4096];   // [64 d][64 kv] swizzled
  __shared__ __align__(16) unsigned short Ps[4][2048];     // per-wave P
  const int tid  = threadIdx.x;
  const int w    = tid >> 6;
  const int lane = tid & 63;
  const int bh   = blockIdx.x;      // b*8 + h
  const int b    = bh >> 3;
  const int h    = bh & 7;
  const int j    = blockIdx.y;      // 0..31
  const int hq   = h*4 + w;         // this wave's query head
  const int cl   = lane & 15;
  const int kgrp = lane >> 4;
  const int rl   = kgrp << 2;
  const int li   = lane >> 3;       // 0..7 (staging row-in-group)
  const int lx   = lane & 7;        // 0..7 (staging chunk)

  const float K2 = 0.125f * 1.44269504088896340736f;  // SCALE * log2(e)

  char* pws = (char*)&Ps[w][0];
  const unsigned swz = ((unsigned)(cl & 7)) << 4;

  bf16x8 ones8;
  #pragma unroll
  for (int q = 0; q < 8; ++q) ones8[q] = (short)0x3F80;   // bf16 1.0

  const char* Kp = (const char*)(K + (size_t)(b*N_)*512 + h*64);
  const char* Vp = (const char*)(Vt + (size_t)(h*64)*BN_ + b*N_);

  // staging constants: instr i covers rows i*8+li; global chunk = (lx^li)
  const unsigned schunk = ((unsigned)(lx ^ li)) << 4;
  const unsigned kso  = (unsigned)li*1024u + schunk;   // + i*8192  + t*65536
  const unsigned vso  = (unsigned)li*8192u + schunk;   // + i*65536 + t*128
  const unsigned ldst = (unsigned)lane*16u;            // + i*1024

  // fragment read offsets: row z*16+cl, chunk (ks*4+kgrp)^(cl&7)
  unsigned rdo[4][2];
  #pragma unroll
  for (int z = 0; z < 4; ++z)
    #pragma unroll
    for (int ks = 0; ks < 2; ++ks)
      rdo[z][ks] = (unsigned)z*2048u + (unsigned)cl*128u
                 + ((((unsigned)ks*4u + (unsigned)kgrp) ^ (unsigned)(cl & 7)) << 4);

  // P LDS offsets: write b64 (4 kv), read b128 (8 kv)
  unsigned wb[2][4], rb[2][2];
  #pragma unroll
  for (int i = 0; i < 2; ++i) {
    #pragma unroll
    for (int c = 0; c < 4; ++c)
      wb[i][c] = (unsigned)i*2048u + (unsigned)cl*128u
               + (((unsigned)c*32u + (unsigned)kgrp*8u) ^ swz);
    #pragma unroll
    for (int ks = 0; ks < 2; ++ks)
      rb[i][ks] = (unsigned)i*2048u + (unsigned)cl*128u
                + (((unsigned)ks*64u + (unsigned)kgrp*16u) ^ swz);
  }

  for (int sp = 0; sp < 2; ++sp) {
    __syncthreads();   // protect LDS buffers from previous strip
    const int sidx = sp ? (63 - j) : j;
    const int q0   = sidx << 5;
    const int nt   = (sidx >> 1) + 1;   // kv tiles of 64

    // Q fragments (B-operand): lane cl = q row
    bf16x8 qf[2][2];
    #pragma unroll
    for (int i = 0; i < 2; ++i) {
      const size_t qoff = (size_t)(b*N_ + q0 + i*16 + cl) * E_ + hq*64 + (kgrp << 3);
      qf[i][0] = *reinterpret_cast<const bf16x8*>(Q + qoff);
      qf[i][1] = *reinterpret_cast<const bf16x8*>(Q + qoff + 32);
    }

    f32x4 o[2][4] = {};
    f32x4 l4[2] = {};
    float m[2] = {-1e30f, -1e30f};

    // stage tile 0 into buffer 0 (each wave: 2 K + 2 V instructions)
    #pragma unroll
    for (int q = 0; q < 2; ++q) {
      const unsigned i = (unsigned)(w*2 + q);
      gload_lds16(Kp + (i*8192u + kso),  (char*)Kbuf[0] + (i*1024u + ldst));
      gload_lds16(Vp + (i*65536u + vso), (char*)Vbuf[0] + (i*1024u + ldst));
    }
    int cur = 0;
    __syncthreads();   // drain stage

    for (int t = 0; t < nt; ++t) {
      // ---- stage tile t+1 into other buffer (overlaps with compute below) ----
      if (t + 1 < nt) {
        const unsigned kt = (unsigned)(t + 1) * 65536u;
        const unsigned vt = (unsigned)(t + 1) * 128u;
        #pragma unroll
        for (int q = 0; q < 2; ++q) {
          const unsigned i = (unsigned)(w*2 + q);
          gload_lds16(Kp + (kt + i*8192u + kso),  (char*)Kbuf[cur^1] + (i*1024u + ldst));
          gload_lds16(Vp + (vt + i*65536u + vso), (char*)Vbuf[cur^1] + (i*1024u + ldst));
        }
      }

      // ---- K fragments from LDS ----
      bf16x8 kf[4][2];
      #pragma unroll
      for (int c = 0; c < 4; ++c)
        #pragma unroll
        for (int ks = 0; ks < 2; ++ks)
          kf[c][ks] = *reinterpret_cast<const bf16x8*>((const char*)Kbuf[cur] + rdo[c][ks]);

      // ---- S^T = K Q ----
      f32x4 s[2][4];
      #pragma unroll
      for (int i = 0; i < 2; ++i)
        #pragma unroll
        for (int c = 0; c < 4; ++c) {
          f32x4 z = {};
          z = MFMA16(kf[c][0], qf[i][0], z);
          z = MFMA16(kf[c][1], qf[i][1], z);
          s[i][c] = z;
        }

      // ---- causal mask (last tile only): kv > q -> -inf ----
      if (t == nt - 1) {
        const int kvb = t << 6;
        #pragma unroll
        for (int i = 0; i < 2; ++i) {
          const int qq = q0 + i*16 + cl;
          #pragma unroll
          for (int c = 0; c < 4; ++c)
            #pragma unroll
            for (int r = 0; r < 4; ++r)
              if (kvb + c*16 + rl + r > qq) s[i][c][r] = -1e30f;
        }
      }

      // ---- softmax per i-block ----
      #pragma unroll
      for (int i = 0; i < 2; ++i) {
        float t0 = fmaxf(fmaxf(s[i][0][0], s[i][0][1]), fmaxf(s[i][0][2], s[i][0][3]));
        float t1 = fmaxf(fmaxf(s[i][1][0], s[i][1][1]), fmaxf(s[i][1][2], s[i][1][3]));
        float t2 = fmaxf(fmaxf(s[i][2][0], s[i][2][1]), fmaxf(s[i][2][2], s[i][2][3]));
        float t3 = fmaxf(fmaxf(s[i][3][0], s[i][3][1]), fmaxf(s[i][3][2], s[i][3][3]));
        float tm = fmaxf(fmaxf(t0, t1), fmaxf(t2, t3));
        tm = fmaxf(tm, __shfl_xor(tm, 16, 64));
        tm = fmaxf(tm, __shfl_xor(tm, 32, 64));
        const float mn = fmaxf(m[i], tm);
        const float al = __builtin_amdgcn_exp2f(K2 * (m[i] - mn));
        m[i] = mn;
        l4[i] *= al;
        #pragma unroll
        for (int db = 0; db < 4; ++db) o[i][db] *= al;
        #pragma unroll
        for (int c = 0; c < 4; ++c) {
          ushort4 u;
          u.x = f2bf(__builtin_amdgcn_exp2f(K2 * (s[i][c][0] - mn)));
          u.y = f2bf(__builtin_amdgcn_exp2f(K2 * (s[i][c][1] - mn)));
          u.z = f2bf(__builtin_amdgcn_exp2f(K2 * (s[i][c][2] - mn)));
          u.w = f2bf(__builtin_amdgcn_exp2f(K2 * (s[i][c][3] - mn)));
          *reinterpret_cast<ushort4*>(pws + wb[i][c]) = u;
        }
      }

      // ---- V fragments from LDS ----
      bf16x8 vf[4][2];
      #pragma unroll
      for (int db = 0; db < 4; ++db)
        #pragma unroll
        for (int ks = 0; ks < 2; ++ks)
          vf[db][ks] = *reinterpret_cast<const bf16x8*>((const char*)Vbuf[cur] + rdo[db][ks]);

      // ---- O^T += V^T P ; l += 1 . P ----
      #pragma unroll
      for (int i = 0; i < 2; ++i) {
        const bf16x8 pa0 = *reinterpret_cast<const bf16x8*>(pws + rb[i][0]);
        const bf16x8 pa1 = *reinterpret_cast<const bf16x8*>(pws + rb[i][1]);
        l4[i] = MFMA16(ones8, pa0, l4[i]);
        l4[i] = MFMA16(ones8, pa1, l4[i]);
        #pragma unroll
        for (int db = 0; db < 4; ++db) {
          o[i][db] = MFMA16(vf[db][0], pa0, o[i][db]);
          o[i][db] = MFMA16(vf[db][1], pa1, o[i][db]);
        }
      }

      __syncthreads();   // stage(t+1) drained + all waves done reading buf[cur]
      cur ^= 1;
    }

    // ---- epilogue: O[q][hq*64 + d] = o/l (contiguous ushort4 per (i,db)) ----
    #pragma unroll
    for (int i = 0; i < 2; ++i) {
      const float inv = 1.0f / l4[i][0];
      const size_t orow = (size_t)(b*N_ + q0 + i*16 + cl) * E_ + hq*64 + rl;
      #pragma unroll
      for (int db = 0; db < 4; ++db) {
        ushort4 u;
        u.x = f2bf(o[i][db][0] * inv);
        u.y = f2bf(o[i][db][1] * inv);
        u.z = f2bf(o[i][db][2] * inv);
        u.w = f2bf(o[i][db][3] * inv);
        *reinterpret_cast<ushort4*>(&O[orow + db*16]) = u;
      }
    }
  }
}

extern "C" void kernel_launch(void* const* d_in, const int* in_sizes, int n_in,
                              void* d_out, int out_size, void* d_ws, size_t ws_size,
                              hipStream_t stream) {
  const float* x  = (const float*)d_in[0];
  const float* Wq = (const float*)d_in[1];
  const float* bq = (const float*)d_in[2];
  const float* Wk = (const float*)d_in[3];
  const float* bk = (const float*)d_in[4];
  const float* Wv = (const float*)d_in[5];
  const float* bv = (const float*)d_in[6];
  const float* Wo = (const float*)d_in[7];
  const float* bo = (const float*)d_in[8];
  float* out = (float*)d_out;

  // workspace carve (bf16 elements); cast destinations contiguous in input order
  unsigned short* ws  = (unsigned short*)d_ws;
  unsigned short* xb  = ws;              // 4096x2048
  unsigned short* Wqb = xb  + 8388608;   // 2048x2048
  unsigned short* Wkb = Wqb + 4194304;   // 512x2048
  unsigned short* Wvb = Wkb + 1048576;   // 512x2048
  unsigned short* Wob = Wvb + 1048576;   // 2048x2048
  unsigned short* Qb  = Wob + 4194304;   // 4096x2048
  unsigned short* Kb  = Qb  + 8388608;   // 4096x512
  unsigned short* Vtb = Kb  + 2097152;   // 512x4096 (V transposed)
  unsigned short* Ob  = Vtb + 2097152;   // 4096x2048

  cast_all<<<dim3(2048), dim3(256), 0, stream>>>(x, Wq, Wk, Wv, Wo, xb);

  gemm_qkv<<<dim3(192), dim3(512), 0, stream>>>(xb, Wqb, Wkb, Wvb,
                                                bq, bk, bv, Qb, Kb, Vtb);

  attn_kernel<<<dim3(16, 32), dim3(256), 0, stream>>>(Qb, Kb, Vtb, Ob);

  gemm_out<<<dim3(256), dim3(512), 0, stream>>>(Ob, Wob, bo, out);
}

// Round 15
// 181.968 us; speedup vs baseline: 1.1239x; 1.1239x over previous
//
#include <hip/hip_runtime.h>
#include <hip/hip_bf16.h>

// FlashMultiHeadAttention: x -> QKV proj -> causal GQA flash attn -> out proj
// B=2 N=2048 E=2048 HQ=32 HKV=8 D=64 G=4. All compute in bf16 MFMA, fp32 accum.

#define B_   2
#define N_   2048
#define E_   2048
#define HQ_  32
#define HKV_ 8
#define D_   64
#define BN_  (B_*N_)   // 4096 total rows

typedef __attribute__((ext_vector_type(8))) short bf16x8;
typedef __attribute__((ext_vector_type(4))) float f32x4;

#define MFMA16(a,b,c) __builtin_amdgcn_mfma_f32_16x16x32_bf16(a,b,c,0,0,0)

__device__ inline unsigned short f2bf(float f) {
  unsigned u = __builtin_bit_cast(unsigned, f);
  u += 0x7FFFu + ((u >> 16) & 1u);   // RNE
  return (unsigned short)(u >> 16);
}

__device__ inline void gload_lds16(const void* g, void* l) {
  __builtin_amdgcn_global_load_lds(
      (const __attribute__((address_space(1))) void*)g,
      (__attribute__((address_space(3))) void*)l, 16, 0, 0);
}

// ---------------- fused cast fp32 -> bf16 for x,Wq,Wk,Wv,Wo ----------------
__global__ void cast_all(const float* __restrict__ x,  const float* __restrict__ wq,
                         const float* __restrict__ wk, const float* __restrict__ wv,
                         const float* __restrict__ wo, unsigned short* __restrict__ dst) {
  const int c0 = 2097152;            // x      (8388608 elems /4)
  const int c1 = c0 + 1048576;       // Wq
  const int c2 = c1 + 262144;        // Wk
  const int c3 = c2 + 262144;        // Wv
  const int c4 = c3 + 1048576;       // Wo
  int i = blockIdx.x * blockDim.x + threadIdx.x;
  const int stride = gridDim.x * blockDim.x;
  for (; i < c4; i += stride) {
    const float* src; int off;
    if      (i < c0) { src = x;  off = i; }
    else if (i < c1) { src = wq; off = i - c0; }
    else if (i < c2) { src = wk; off = i - c1; }
    else if (i < c3) { src = wv; off = i - c2; }
    else             { src = wo; off = i - c3; }
    float4 f = reinterpret_cast<const float4*>(src)[off];
    ushort4 u;
    u.x = f2bf(f.x); u.y = f2bf(f.y); u.z = f2bf(f.z); u.w = f2bf(f.w);
    reinterpret_cast<ushort4*>(dst)[i] = u;
  }
}

// ---------------- fused QKV projection GEMM: 128x192 tile, EXACT 2-blocks/CU ------
// BM=128, BN=192 (virtual QKV cols 3072 = 16 x 192), BK=64. Grid 32x16 = 512
// blocks = exactly 2 per CU (LDS 80KB x 2 = 160KB; __launch_bounds__(512,4) caps
// VGPR at 128 so both blocks reside). 512 thr = 8 waves (2M x 4N), per-wave
// 64x48 (acc[4][3]). LDS dbuf: As[2][128x64] + Bs[2][192x64]. Thin counted-vmcnt
// schedule: per tile {STAGE(t+1)->buf^1 (5 wave-loads: 2 A + 3 B) -> vmcnt(5)
// (tile-t landed; t+1 in flight ACROSS barriers) -> s_barrier -> 2 ks x
// (7 ds_read_b128 + setprio'd 12 MFMA) -> s_barrier}. Both-sides XOR swizzle
// (v9/v12-verified, 0 conflicts). Segment boundaries 2048/2560 are multiples of
// 8 (staging) and 16 (epilogue) -> per-instr / per-frag uniform segment.
// Cross-block wave overlap (2 blocks/CU) hides the stage drain (m114).
__global__ __launch_bounds__(512, 4) void gemm_qkv(
    const unsigned short* __restrict__ A,
    const unsigned short* __restrict__ Wq, const unsigned short* __restrict__ Wk,
    const unsigned short* __restrict__ Wv,
    const float* __restrict__ bq, const float* __restrict__ bk, const float* __restrict__ bv,
    unsigned short* __restrict__ Qo, unsigned short* __restrict__ Ko,
    unsigned short* __restrict__ Vto)
{
  __shared__ __align__(16) unsigned short As[2][8192];    // [buf][128*64]  2x16KB
  __shared__ __align__(16) unsigned short Bs[2][12288];   // [buf][192*64]  2x24KB
  const int tid  = threadIdx.x;
  const int w    = tid >> 6;
  const int lane = tid & 63;
  const int g    = blockIdx.x & 7;        // XCD slot
  const int s    = blockIdx.x >> 3;       // 0..63
  const int bm   = g*4 + (s >> 4);        // 0..31 (4 bm-panels per XCD)
  const int bn   = s & 15;                // 0..15
  const int m0   = bm << 7;
  const int n0v  = bn * 192;              // virtual col in [Q|K|V] = 3072
  const int K    = E_;

  const int mgrp = w >> 2;                // 0/1: rows mgrp*64
  const int ngrp = w & 3;                 // cols ngrp*48
  const int cl   = lane & 15;
  const int kgrp = lane >> 4;
  const int rl   = kgrp << 2;
  const int li   = lane >> 3;             // staging row-in-group 0..7
  const int lx   = lane & 7;              // staging chunk 0..7

  // staging bases; global chunk = lx^li (inverse swizzle)
  const unsigned gsw = ((unsigned)(lx ^ li)) << 3;   // elems
  const unsigned short* gA = A + (size_t)(m0 + w*16 + li) * K + gsw;
  const unsigned short* gBq[3];
  #pragma unroll
  for (int q = 0; q < 3; ++q) {
    const int vr = n0v + w*24 + q*8;      // seg-uniform (2048/2560 % 8 == 0)
    const unsigned short* base;
    if (vr < 2048)      base = Wq + (size_t)vr * K;
    else if (vr < 2560) base = Wk + (size_t)(vr - 2048) * K;
    else                base = Wv + (size_t)(vr - 2560) * K;
    gBq[q] = base + (size_t)li * K + gsw;
  }
  const unsigned aDst = (unsigned)(w*16)*64u + (unsigned)lane*8u;  // elems
  const unsigned bDst = (unsigned)(w*24)*64u + (unsigned)lane*8u;

  // read offsets (elems): row*64 + ((ks*4+kgrp)^(cl&7))*8
  unsigned rAo[4][2], rBo[3][2];
  #pragma unroll
  for (int ks = 0; ks < 2; ++ks) {
    const unsigned c8 = (((unsigned)(ks*4 + kgrp)) ^ (unsigned)(cl & 7)) << 3;
    #pragma unroll
    for (int z = 0; z < 4; ++z)
      rAo[z][ks] = (unsigned)(mgrp*64 + z*16 + cl) * 64u + c8;
    #pragma unroll
    for (int jj = 0; jj < 3; ++jj)
      rBo[jj][ks] = (unsigned)(ngrp*48 + jj*16 + cl) * 64u + c8;
  }

  f32x4 acc[4][3] = {};
  const int nt = K >> 6;   // 32

  auto STAGE = [&](int kt, int buf) {   // 5 wave-loads: 2 A + 3 B
    const int ko = kt << 6;
    #pragma unroll
    for (int q = 0; q < 2; ++q)
      gload_lds16(gA + (size_t)(q*8)*K + ko, &As[buf][aDst + q*512u]);
    #pragma unroll
    for (int q = 0; q < 3; ++q)
      gload_lds16(gBq[q] + ko, &Bs[buf][bDst + q*512u]);
  };

  STAGE(0, 0);
  int p = 0;

  for (int t = 0; t < nt; ++t) {
    if (t + 1 < nt) {
      STAGE(t + 1, p ^ 1);
      asm volatile("s_waitcnt vmcnt(5)" ::: "memory");   // tile-t landed
    } else {
      asm volatile("s_waitcnt vmcnt(0)" ::: "memory");
    }
    __builtin_amdgcn_s_barrier();
    #pragma unroll
    for (int ks = 0; ks < 2; ++ks) {
      bf16x8 af[4], bfr[3];
      #pragma unroll
      for (int z = 0; z < 4; ++z)
        af[z] = *reinterpret_cast<const bf16x8*>(&As[p][rAo[z][ks]]);
      #pragma unroll
      for (int jj = 0; jj < 3; ++jj)
        bfr[jj] = *reinterpret_cast<const bf16x8*>(&Bs[p][rBo[jj][ks]]);
      __builtin_amdgcn_s_setprio(1);
      #pragma unroll
      for (int z = 0; z < 4; ++z)
        #pragma unroll
        for (int jj = 0; jj < 3; ++jj)
          acc[z][jj] = MFMA16(af[z], bfr[jj], acc[z][jj]);
      __builtin_amdgcn_s_setprio(0);
    }
    __builtin_amdgcn_s_barrier();   // reads consumed -> safe to restage buf p
    p ^= 1;
  }

  // epilogue: per-(jj) 16-col fragment is segment-uniform (2048/2560 % 16 == 0)
  #pragma unroll
  for (int z = 0; z < 4; ++z) {
    const int rowb = m0 + mgrp*64 + z*16 + rl;
    #pragma unroll
    for (int jj = 0; jj < 3; ++jj) {
      const int col16 = n0v + ngrp*48 + jj*16;
      if (col16 < 2048) {
        const int col = col16 + cl;
        const float bj = bq[col];
        #pragma unroll
        for (int r = 0; r < 4; ++r)
          Qo[(size_t)(rowb + r) * 2048 + col] = f2bf(acc[z][jj][r] + bj);
      } else if (col16 < 2560) {
        const int col = col16 - 2048 + cl;
        const float bj = bk[col];
        #pragma unroll
        for (int r = 0; r < 4; ++r)
          Ko[(size_t)(rowb + r) * 512 + col] = f2bf(acc[z][jj][r] + bj);
      } else {
        const int col = col16 - 2560 + cl;
        const float bj = bv[col];
        ushort4 u;
        u.x = f2bf(acc[z][jj][0] + bj);
        u.y = f2bf(acc[z][jj][1] + bj);
        u.z = f2bf(acc[z][jj][2] + bj);
        u.w = f2bf(acc[z][jj][3] + bj);
        *reinterpret_cast<ushort4*>(&Vto[(size_t)col * 4096 + rowb]) = u;
      }
    }
  }
}

// ---------------- out-proj GEMM (v9 engine: BK=64 single-buffer, fp32 out) --------
__global__ __launch_bounds__(256) void gemm_out(
    const unsigned short* __restrict__ A, const unsigned short* __restrict__ W,
    const float* __restrict__ bias, float* __restrict__ C)
{
  __shared__ __align__(16) unsigned short As[128*64];
  __shared__ __align__(16) unsigned short Bs[128*64];
  const int tid  = threadIdx.x;
  const int w    = tid >> 6;
  const int lane = tid & 63;
  const int bm   = blockIdx.x >> 4;
  const int bn   = blockIdx.x & 15;
  const int m0   = bm << 7, n0 = bn << 7;
  const int K    = E_;
  const int wr   = (w >> 1) << 6;
  const int wc   = (w & 1) << 6;
  const int cl   = lane & 15;
  const int kgrp = lane >> 4;
  const int rl   = kgrp << 2;
  const int li   = lane >> 3;
  const int lx   = lane & 7;

  const unsigned schunk = ((unsigned)(lx ^ li)) << 3;
  const unsigned short* gA = A + (size_t)(m0 + li) * K + schunk;
  const unsigned short* gB = W + (size_t)(n0 + li) * K + schunk;
  unsigned short* lA = As + lane*8;
  unsigned short* lB = Bs + lane*8;

  unsigned rA[4][2], rB[4][2];
  #pragma unroll
  for (int z = 0; z < 4; ++z)
    #pragma unroll
    for (int ks = 0; ks < 2; ++ks) {
      rA[z][ks] = (unsigned)(wr + z*16 + cl)*64u + ((((unsigned)ks*4u + (unsigned)kgrp) ^ (unsigned)(cl & 7)) << 3);
      rB[z][ks] = (unsigned)(wc + z*16 + cl)*64u + ((((unsigned)ks*4u + (unsigned)kgrp) ^ (unsigned)(cl & 7)) << 3);
    }

  f32x4 acc[4][4] = {};

  for (int kt = 0; kt < (K >> 6); ++kt) {
    const int ko = kt << 6;
    #pragma unroll
    for (int q = 0; q < 4; ++q) {
      const unsigned i = (unsigned)(w*4 + q);
      gload_lds16(gA + ((size_t)i*8*K + ko), lA + i*512);
      gload_lds16(gB + ((size_t)i*8*K + ko), lB + i*512);
    }
    __syncthreads();
    #pragma unroll
    for (int ks = 0; ks < 2; ++ks) {
      bf16x8 af[4], bfr[4];
      #pragma unroll
      for (int i = 0; i < 4; ++i)
        af[i] = *reinterpret_cast<const bf16x8*>(&As[rA[i][ks]]);
      #pragma unroll
      for (int j = 0; j < 4; ++j)
        bfr[j] = *reinterpret_cast<const bf16x8*>(&Bs[rB[j][ks]]);
      #pragma unroll
      for (int i = 0; i < 4; ++i)
        #pragma unroll
        for (int j = 0; j < 4; ++j)
          acc[i][j] = MFMA16(af[i], bfr[j], acc[i][j]);
    }
    __syncthreads();
  }

  #pragma unroll
  for (int j = 0; j < 4; ++j) {
    const int col = n0 + wc + j*16 + cl;
    const float bj = bias[col];
    #pragma unroll
    for (int i = 0; i < 4; ++i) {
      const int row = m0 + wr + i*16 + rl;
      #pragma unroll
      for (int r = 0; r < 4; ++r)
        C[(size_t)(row + r) * E_ + col] = acc[i][j][r] + bj;
    }
  }
}

// ---------------- causal GQA flash attention (v8: LDS-staged shared K/V) ----------
// grid (16, 32): x = bh = b*8+h, y = pair j. Block = 4 waves = the 4 query heads
// sharing (b,h)'s K/V. All waves handle the SAME balanced 32-row strip pair
// (j, 63-j) -> identical nt -> lockstep barriers. Per kv tile (64 kv): K tile and
// V^T tile (8KB each) staged into double-buffered LDS by 16 coalesced
// global_load_lds, stage-ahead of compute. Both-sides XOR chunk swizzle.
// Compute engine: S^T = mfma(K,Q), lane-local softmax, P via swizzled per-wave
// LDS, O^T = mfma(V^T,P), l via ones-MFMA.
__global__ __launch_bounds__(256, 2) void attn_kernel(
    const unsigned short* __restrict__ Q, const unsigned short* __restrict__ K,
    const unsigned short* __restrict__ Vt, unsigned short* __restrict__ O)
{
  __shared__ __align__(16) unsigned short Kbuf[2][4096];   // [64 kv][64 d] swizzled
  __shared__ __align__(16) unsigned short Vbuf[2][4096];   // [64 d][64 kv] swizzled
  __shared__ __align__(16) unsigned short Ps[4][2048];     // per-wave P
  const int tid  = threadIdx.x;
  const int w    = tid >> 6;
  const int lane = tid & 63;
  const int bh   = blockIdx.x;      // b*8 + h
  const int b    = bh >> 3;
  const int h    = bh & 7;
  const int j    = blockIdx.y;      // 0..31
  const int hq   = h*4 + w;         // this wave's query head
  const int cl   = lane & 15;
  const int kgrp = lane >> 4;
  const int rl   = kgrp << 2;
  const int li   = lane >> 3;       // 0..7 (staging row-in-group)
  const int lx   = lane & 7;        // 0..7 (staging chunk)

  const float K2 = 0.125f * 1.44269504088896340736f;  // SCALE * log2(e)

  char* pws = (char*)&Ps[w][0];
  const unsigned swz = ((unsigned)(cl & 7)) << 4;

  bf16x8 ones8;
  #pragma unroll
  for (int q = 0; q < 8; ++q) ones8[q] = (short)0x3F80;   // bf16 1.0

  const char* Kp = (const char*)(K + (size_t)(b*N_)*512 + h*64);
  const char* Vp = (const char*)(Vt + (size_t)(h*64)*BN_ + b*N_);

  // staging constants: instr i covers rows i*8+li; global chunk = (lx^li)
  const unsigned schunk = ((unsigned)(lx ^ li)) << 4;
  const unsigned kso  = (unsigned)li*1024u + schunk;   // + i*8192  + t*65536
  const unsigned vso  = (unsigned)li*8192u + schunk;   // + i*65536 + t*128
  const unsigned ldst = (unsigned)lane*16u;            // + i*1024

  // fragment read offsets: row z*16+cl, chunk (ks*4+kgrp)^(cl&7)
  unsigned rdo[4][2];
  #pragma unroll
  for (int z = 0; z < 4; ++z)
    #pragma unroll
    for (int ks = 0; ks < 2; ++ks)
      rdo[z][ks] = (unsigned)z*2048u + (unsigned)cl*128u
                 + ((((unsigned)ks*4u + (unsigned)kgrp) ^ (unsigned)(cl & 7)) << 4);

  // P LDS offsets: write b64 (4 kv), read b128 (8 kv)
  unsigned wb[2][4], rb[2][2];
  #pragma unroll
  for (int i = 0; i < 2; ++i) {
    #pragma unroll
    for (int c = 0; c < 4; ++c)
      wb[i][c] = (unsigned)i*2048u + (unsigned)cl*128u
               + (((unsigned)c*32u + (unsigned)kgrp*8u) ^ swz);
    #pragma unroll
    for (int ks = 0; ks < 2; ++ks)
      rb[i][ks] = (unsigned)i*2048u + (unsigned)cl*128u
                + (((unsigned)ks*64u + (unsigned)kgrp*16u) ^ swz);
  }

  for (int sp = 0; sp < 2; ++sp) {
    __syncthreads();   // protect LDS buffers from previous strip
    const int sidx = sp ? (63 - j) : j;
    const int q0   = sidx << 5;
    const int nt   = (sidx >> 1) + 1;   // kv tiles of 64

    // Q fragments (B-operand): lane cl = q row
    bf16x8 qf[2][2];
    #pragma unroll
    for (int i = 0; i < 2; ++i) {
      const size_t qoff = (size_t)(b*N_ + q0 + i*16 + cl) * E_ + hq*64 + (kgrp << 3);
      qf[i][0] = *reinterpret_cast<const bf16x8*>(Q + qoff);
      qf[i][1] = *reinterpret_cast<const bf16x8*>(Q + qoff + 32);
    }

    f32x4 o[2][4] = {};
    f32x4 l4[2] = {};
    float m[2] = {-1e30f, -1e30f};

    // stage tile 0 into buffer 0 (each wave: 2 K + 2 V instructions)
    #pragma unroll
    for (int q = 0; q < 2; ++q) {
      const unsigned i = (unsigned)(w*2 + q);
      gload_lds16(Kp + (i*8192u + kso),  (char*)Kbuf[0] + (i*1024u + ldst));
      gload_lds16(Vp + (i*65536u + vso), (char*)Vbuf[0] + (i*1024u + ldst));
    }
    int cur = 0;
    __syncthreads();   // drain stage

    for (int t = 0; t < nt; ++t) {
      // ---- stage tile t+1 into other buffer (overlaps with compute below) ----
      if (t + 1 < nt) {
        const unsigned kt = (unsigned)(t + 1) * 65536u;
        const unsigned vt = (unsigned)(t + 1) * 128u;
        #pragma unroll
        for (int q = 0; q < 2; ++q) {
          const unsigned i = (unsigned)(w*2 + q);
          gload_lds16(Kp + (kt + i*8192u + kso),  (char*)Kbuf[cur^1] + (i*1024u + ldst));
          gload_lds16(Vp + (vt + i*65536u + vso), (char*)Vbuf[cur^1] + (i*1024u + ldst));
        }
      }

      // ---- K fragments from LDS ----
      bf16x8 kf[4][2];
      #pragma unroll
      for (int c = 0; c < 4; ++c)
        #pragma unroll
        for (int ks = 0; ks < 2; ++ks)
          kf[c][ks] = *reinterpret_cast<const bf16x8*>((const char*)Kbuf[cur] + rdo[c][ks]);

      // ---- S^T = K Q ----
      f32x4 s[2][4];
      #pragma unroll
      for (int i = 0; i < 2; ++i)
        #pragma unroll
        for (int c = 0; c < 4; ++c) {
          f32x4 z = {};
          z = MFMA16(kf[c][0], qf[i][0], z);
          z = MFMA16(kf[c][1], qf[i][1], z);
          s[i][c] = z;
        }

      // ---- causal mask (last tile only): kv > q -> -inf ----
      if (t == nt - 1) {
        const int kvb = t << 6;
        #pragma unroll
        for (int i = 0; i < 2; ++i) {
          const int qq = q0 + i*16 + cl;
          #pragma unroll
          for (int c = 0; c < 4; ++c)
            #pragma unroll
            for (int r = 0; r < 4; ++r)
              if (kvb + c*16 + rl + r > qq) s[i][c][r] = -1e30f;
        }
      }

      // ---- softmax per i-block ----
      #pragma unroll
      for (int i = 0; i < 2; ++i) {
        float t0 = fmaxf(fmaxf(s[i][0][0], s[i][0][1]), fmaxf(s[i][0][2], s[i][0][3]));
        float t1 = fmaxf(fmaxf(s[i][1][0], s[i][1][1]), fmaxf(s[i][1][2], s[i][1][3]));
        float t2 = fmaxf(fmaxf(s[i][2][0], s[i][2][1]), fmaxf(s[i][2][2], s[i][2][3]));
        float t3 = fmaxf(fmaxf(s[i][3][0], s[i][3][1]), fmaxf(s[i][3][2], s[i][3][3]));
        float tm = fmaxf(fmaxf(t0, t1), fmaxf(t2, t3));
        tm = fmaxf(tm, __shfl_xor(tm, 16, 64));
        tm = fmaxf(tm, __shfl_xor(tm, 32, 64));
        const float mn = fmaxf(m[i], tm);
        const float al = __builtin_amdgcn_exp2f(K2 * (m[i] - mn));
        m[i] = mn;
        l4[i] *= al;
        #pragma unroll
        for (int db = 0; db < 4; ++db) o[i][db] *= al;
        #pragma unroll
        for (int c = 0; c < 4; ++c) {
          ushort4 u;
          u.x = f2bf(__builtin_amdgcn_exp2f(K2 * (s[i][c][0] - mn)));
          u.y = f2bf(__builtin_amdgcn_exp2f(K2 * (s[i][c][1] - mn)));
          u.z = f2bf(__builtin_amdgcn_exp2f(K2 * (s[i][c][2] - mn)));
          u.w = f2bf(__builtin_amdgcn_exp2f(K2 * (s[i][c][3] - mn)));
          *reinterpret_cast<ushort4*>(pws + wb[i][c]) = u;
        }
      }

      // ---- V fragments from LDS ----
      bf16x8 vf[4][2];
      #pragma unroll
      for (int db = 0; db < 4; ++db)
        #pragma unroll
        for (int ks = 0; ks < 2; ++ks)
          vf[db][ks] = *reinterpret_cast<const bf16x8*>((const char*)Vbuf[cur] + rdo[db][ks]);

      // ---- O^T += V^T P ; l += 1 . P ----
      #pragma unroll
      for (int i = 0; i < 2; ++i) {
        const bf16x8 pa0 = *reinterpret_cast<const bf16x8*>(pws + rb[i][0]);
        const bf16x8 pa1 = *reinterpret_cast<const bf16x8*>(pws + rb[i][1]);
        l4[i] = MFMA16(ones8, pa0, l4[i]);
        l4[i] = MFMA16(ones8, pa1, l4[i]);
        #pragma unroll
        for (int db = 0; db < 4; ++db) {
          o[i][db] = MFMA16(vf[db][0], pa0, o[i][db]);
          o[i][db] = MFMA16(vf[db][1], pa1, o[i][db]);
        }
      }

      __syncthreads();   // stage(t+1) drained + all waves done reading buf[cur]
      cur ^= 1;
    }

    // ---- epilogue: O[q][hq*64 + d] = o/l (contiguous ushort4 per (i,db)) ----
    #pragma unroll
    for (int i = 0; i < 2; ++i) {
      const float inv = 1.0f / l4[i][0];
      const size_t orow = (size_t)(b*N_ + q0 + i*16 + cl) * E_ + hq*64 + rl;
      #pragma unroll
      for (int db = 0; db < 4; ++db) {
        ushort4 u;
        u.x = f2bf(o[i][db][0] * inv);
        u.y = f2bf(o[i][db][1] * inv);
        u.z = f2bf(o[i][db][2] * inv);
        u.w = f2bf(o[i][db][3] * inv);
        *reinterpret_cast<ushort4*>(&O[orow + db*16]) = u;
      }
    }
  }
}

extern "C" void kernel_launch(void* const* d_in, const int* in_sizes, int n_in,
                              void* d_out, int out_size, void* d_ws, size_t ws_size,
                              hipStream_t stream) {
  const float* x  = (const float*)d_in[0];
  const float* Wq = (const float*)d_in[1];
  const float* bq = (const float*)d_in[2];
  const float* Wk = (const float*)d_in[3];
  const float* bk = (const float*)d_in[4];
  const float* Wv = (const float*)d_in[5];
  const float* bv = (const float*)d_in[6];
  const float* Wo = (const float*)d_in[7];
  const float* bo = (const float*)d_in[8];
  float* out = (float*)d_out;

  // workspace carve (bf16 elements); cast destinations contiguous in input order
  unsigned short* ws  = (unsigned short*)d_ws;
  unsigned short* xb  = ws;              // 4096x2048
  unsigned short* Wqb = xb  + 8388608;   // 2048x2048
  unsigned short* Wkb = Wqb + 4194304;   // 512x2048
  unsigned short* Wvb = Wkb + 1048576;   // 512x2048
  unsigned short* Wob = Wvb + 1048576;   // 2048x2048
  unsigned short* Qb  = Wob + 4194304;   // 4096x2048
  unsigned short* Kb  = Qb  + 8388608;   // 4096x512
  unsigned short* Vtb = Kb  + 2097152;   // 512x4096 (V transposed)
  unsigned short* Ob  = Vtb + 2097152;   // 4096x2048

  cast_all<<<dim3(2048), dim3(256), 0, stream>>>(x, Wq, Wk, Wv, Wo, xb);

  gemm_qkv<<<dim3(512), dim3(512), 0, stream>>>(xb, Wqb, Wkb, Wvb,
                                                bq, bk, bv, Qb, Kb, Vtb);

  attn_kernel<<<dim3(16, 32), dim3(256), 0, stream>>>(Qb, Kb, Vtb, Ob);

  gemm_out<<<dim3(32*16), dim3(256), 0, stream>>>(Ob, Wob, bo, out);
}

// Round 16
// 176.268 us; speedup vs baseline: 1.1602x; 1.0323x over previous
//
#include <hip/hip_runtime.h>
#include <hip/hip_bf16.h>

// FlashMultiHeadAttention: x -> QKV proj -> causal GQA flash attn -> out proj
// B=2 N=2048 E=2048 HQ=32 HKV=8 D=64 G=4. All compute in bf16 MFMA, fp32 accum.

#define B_   2
#define N_   2048
#define E_   2048
#define HQ_  32
#define HKV_ 8
#define D_   64
#define BN_  (B_*N_)   // 4096 total rows

typedef __attribute__((ext_vector_type(8))) short bf16x8;
typedef __attribute__((ext_vector_type(4))) float f32x4;

#define MFMA16(a,b,c) __builtin_amdgcn_mfma_f32_16x16x32_bf16(a,b,c,0,0,0)

__device__ inline unsigned short f2bf(float f) {
  unsigned u = __builtin_bit_cast(unsigned, f);
  u += 0x7FFFu + ((u >> 16) & 1u);   // RNE
  return (unsigned short)(u >> 16);
}

__device__ inline void gload_lds16(const void* g, void* l) {
  __builtin_amdgcn_global_load_lds(
      (const __attribute__((address_space(1))) void*)g,
      (__attribute__((address_space(3))) void*)l, 16, 0, 0);
}

// ---------------- fused cast fp32 -> bf16 for x,Wq,Wk,Wv,Wo ----------------
__global__ void cast_all(const float* __restrict__ x,  const float* __restrict__ wq,
                         const float* __restrict__ wk, const float* __restrict__ wv,
                         const float* __restrict__ wo, unsigned short* __restrict__ dst) {
  const int c0 = 2097152;            // x      (8388608 elems /4)
  const int c1 = c0 + 1048576;       // Wq
  const int c2 = c1 + 262144;        // Wk
  const int c3 = c2 + 262144;        // Wv
  const int c4 = c3 + 1048576;       // Wo
  int i = blockIdx.x * blockDim.x + threadIdx.x;
  const int stride = gridDim.x * blockDim.x;
  for (; i < c4; i += stride) {
    const float* src; int off;
    if      (i < c0) { src = x;  off = i; }
    else if (i < c1) { src = wq; off = i - c0; }
    else if (i < c2) { src = wk; off = i - c1; }
    else if (i < c3) { src = wv; off = i - c2; }
    else             { src = wo; off = i - c3; }
    float4 f = reinterpret_cast<const float4*>(src)[off];
    ushort4 u;
    u.x = f2bf(f.x); u.y = f2bf(f.y); u.z = f2bf(f.z); u.w = f2bf(f.w);
    reinterpret_cast<ushort4*>(dst)[i] = u;
  }
}

// ---------------- fused QKV projection GEMM: 128x192 tile, EXACT 2-blocks/CU ------
// (v15-verified) BM=128, BN=192 (virtual QKV cols 3072 = 16 x 192), BK=64.
// Grid 512 = exactly 2 per CU. 8 waves (2M x 4N), per-wave 64x48 (acc[4][3]).
// LDS dbuf: As[2][128x64] + Bs[2][192x64] = 80KB. Thin counted-vmcnt schedule.
__global__ __launch_bounds__(512, 4) void gemm_qkv(
    const unsigned short* __restrict__ A,
    const unsigned short* __restrict__ Wq, const unsigned short* __restrict__ Wk,
    const unsigned short* __restrict__ Wv,
    const float* __restrict__ bq, const float* __restrict__ bk, const float* __restrict__ bv,
    unsigned short* __restrict__ Qo, unsigned short* __restrict__ Ko,
    unsigned short* __restrict__ Vto)
{
  __shared__ __align__(16) unsigned short As[2][8192];    // [buf][128*64]  2x16KB
  __shared__ __align__(16) unsigned short Bs[2][12288];   // [buf][192*64]  2x24KB
  const int tid  = threadIdx.x;
  const int w    = tid >> 6;
  const int lane = tid & 63;
  const int g    = blockIdx.x & 7;        // XCD slot
  const int s    = blockIdx.x >> 3;       // 0..63
  const int bm   = g*4 + (s >> 4);        // 0..31 (4 bm-panels per XCD)
  const int bn   = s & 15;                // 0..15
  const int m0   = bm << 7;
  const int n0v  = bn * 192;              // virtual col in [Q|K|V] = 3072
  const int K    = E_;

  const int mgrp = w >> 2;                // 0/1: rows mgrp*64
  const int ngrp = w & 3;                 // cols ngrp*48
  const int cl   = lane & 15;
  const int kgrp = lane >> 4;
  const int rl   = kgrp << 2;
  const int li   = lane >> 3;             // staging row-in-group 0..7
  const int lx   = lane & 7;              // staging chunk 0..7

  // staging bases; global chunk = lx^li (inverse swizzle)
  const unsigned gsw = ((unsigned)(lx ^ li)) << 3;   // elems
  const unsigned short* gA = A + (size_t)(m0 + w*16 + li) * K + gsw;
  const unsigned short* gBq[3];
  #pragma unroll
  for (int q = 0; q < 3; ++q) {
    const int vr = n0v + w*24 + q*8;      // seg-uniform (2048/2560 % 8 == 0)
    const unsigned short* base;
    if (vr < 2048)      base = Wq + (size_t)vr * K;
    else if (vr < 2560) base = Wk + (size_t)(vr - 2048) * K;
    else                base = Wv + (size_t)(vr - 2560) * K;
    gBq[q] = base + (size_t)li * K + gsw;
  }
  const unsigned aDst = (unsigned)(w*16)*64u + (unsigned)lane*8u;  // elems
  const unsigned bDst = (unsigned)(w*24)*64u + (unsigned)lane*8u;

  // read offsets (elems): row*64 + ((ks*4+kgrp)^(cl&7))*8
  unsigned rAo[4][2], rBo[3][2];
  #pragma unroll
  for (int ks = 0; ks < 2; ++ks) {
    const unsigned c8 = (((unsigned)(ks*4 + kgrp)) ^ (unsigned)(cl & 7)) << 3;
    #pragma unroll
    for (int z = 0; z < 4; ++z)
      rAo[z][ks] = (unsigned)(mgrp*64 + z*16 + cl) * 64u + c8;
    #pragma unroll
    for (int jj = 0; jj < 3; ++jj)
      rBo[jj][ks] = (unsigned)(ngrp*48 + jj*16 + cl) * 64u + c8;
  }

  f32x4 acc[4][3] = {};
  const int nt = K >> 6;   // 32

  auto STAGE = [&](int kt, int buf) {   // 5 wave-loads: 2 A + 3 B
    const int ko = kt << 6;
    #pragma unroll
    for (int q = 0; q < 2; ++q)
      gload_lds16(gA + (size_t)(q*8)*K + ko, &As[buf][aDst + q*512u]);
    #pragma unroll
    for (int q = 0; q < 3; ++q)
      gload_lds16(gBq[q] + ko, &Bs[buf][bDst + q*512u]);
  };

  STAGE(0, 0);
  int p = 0;

  for (int t = 0; t < nt; ++t) {
    if (t + 1 < nt) {
      STAGE(t + 1, p ^ 1);
      asm volatile("s_waitcnt vmcnt(5)" ::: "memory");   // tile-t landed
    } else {
      asm volatile("s_waitcnt vmcnt(0)" ::: "memory");
    }
    __builtin_amdgcn_s_barrier();
    #pragma unroll
    for (int ks = 0; ks < 2; ++ks) {
      bf16x8 af[4], bfr[3];
      #pragma unroll
      for (int z = 0; z < 4; ++z)
        af[z] = *reinterpret_cast<const bf16x8*>(&As[p][rAo[z][ks]]);
      #pragma unroll
      for (int jj = 0; jj < 3; ++jj)
        bfr[jj] = *reinterpret_cast<const bf16x8*>(&Bs[p][rBo[jj][ks]]);
      __builtin_amdgcn_s_setprio(1);
      #pragma unroll
      for (int z = 0; z < 4; ++z)
        #pragma unroll
        for (int jj = 0; jj < 3; ++jj)
          acc[z][jj] = MFMA16(af[z], bfr[jj], acc[z][jj]);
      __builtin_amdgcn_s_setprio(0);
    }
    __builtin_amdgcn_s_barrier();   // reads consumed -> safe to restage buf p
    p ^= 1;
  }

  // epilogue: per-(jj) 16-col fragment is segment-uniform (2048/2560 % 16 == 0)
  #pragma unroll
  for (int z = 0; z < 4; ++z) {
    const int rowb = m0 + mgrp*64 + z*16 + rl;
    #pragma unroll
    for (int jj = 0; jj < 3; ++jj) {
      const int col16 = n0v + ngrp*48 + jj*16;
      if (col16 < 2048) {
        const int col = col16 + cl;
        const float bj = bq[col];
        #pragma unroll
        for (int r = 0; r < 4; ++r)
          Qo[(size_t)(rowb + r) * 2048 + col] = f2bf(acc[z][jj][r] + bj);
      } else if (col16 < 2560) {
        const int col = col16 - 2048 + cl;
        const float bj = bk[col];
        #pragma unroll
        for (int r = 0; r < 4; ++r)
          Ko[(size_t)(rowb + r) * 512 + col] = f2bf(acc[z][jj][r] + bj);
      } else {
        const int col = col16 - 2560 + cl;
        const float bj = bv[col];
        ushort4 u;
        u.x = f2bf(acc[z][jj][0] + bj);
        u.y = f2bf(acc[z][jj][1] + bj);
        u.z = f2bf(acc[z][jj][2] + bj);
        u.w = f2bf(acc[z][jj][3] + bj);
        *reinterpret_cast<ushort4*>(&Vto[(size_t)col * 4096 + rowb]) = u;
      }
    }
  }
}

// ---------------- out-proj GEMM (v9 engine: BK=64 single-buffer, fp32 out) --------
__global__ __launch_bounds__(256) void gemm_out(
    const unsigned short* __restrict__ A, const unsigned short* __restrict__ W,
    const float* __restrict__ bias, float* __restrict__ C)
{
  __shared__ __align__(16) unsigned short As[128*64];
  __shared__ __align__(16) unsigned short Bs[128*64];
  const int tid  = threadIdx.x;
  const int w    = tid >> 6;
  const int lane = tid & 63;
  const int bm   = blockIdx.x >> 4;
  const int bn   = blockIdx.x & 15;
  const int m0   = bm << 7, n0 = bn << 7;
  const int K    = E_;
  const int wr   = (w >> 1) << 6;
  const int wc   = (w & 1) << 6;
  const int cl   = lane & 15;
  const int kgrp = lane >> 4;
  const int rl   = kgrp << 2;
  const int li   = lane >> 3;
  const int lx   = lane & 7;

  const unsigned schunk = ((unsigned)(lx ^ li)) << 3;
  const unsigned short* gA = A + (size_t)(m0 + li) * K + schunk;
  const unsigned short* gB = W + (size_t)(n0 + li) * K + schunk;
  unsigned short* lA = As + lane*8;
  unsigned short* lB = Bs + lane*8;

  unsigned rA[4][2], rB[4][2];
  #pragma unroll
  for (int z = 0; z < 4; ++z)
    #pragma unroll
    for (int ks = 0; ks < 2; ++ks) {
      rA[z][ks] = (unsigned)(wr + z*16 + cl)*64u + ((((unsigned)ks*4u + (unsigned)kgrp) ^ (unsigned)(cl & 7)) << 3);
      rB[z][ks] = (unsigned)(wc + z*16 + cl)*64u + ((((unsigned)ks*4u + (unsigned)kgrp) ^ (unsigned)(cl & 7)) << 3);
    }

  f32x4 acc[4][4] = {};

  for (int kt = 0; kt < (K >> 6); ++kt) {
    const int ko = kt << 6;
    #pragma unroll
    for (int q = 0; q < 4; ++q) {
      const unsigned i = (unsigned)(w*4 + q);
      gload_lds16(gA + ((size_t)i*8*K + ko), lA + i*512);
      gload_lds16(gB + ((size_t)i*8*K + ko), lB + i*512);
    }
    __syncthreads();
    #pragma unroll
    for (int ks = 0; ks < 2; ++ks) {
      bf16x8 af[4], bfr[4];
      #pragma unroll
      for (int i = 0; i < 4; ++i)
        af[i] = *reinterpret_cast<const bf16x8*>(&As[rA[i][ks]]);
      #pragma unroll
      for (int j = 0; j < 4; ++j)
        bfr[j] = *reinterpret_cast<const bf16x8*>(&Bs[rB[j][ks]]);
      #pragma unroll
      for (int i = 0; i < 4; ++i)
        #pragma unroll
        for (int j = 0; j < 4; ++j)
          acc[i][j] = MFMA16(af[i], bfr[j], acc[i][j]);
    }
    __syncthreads();
  }

  #pragma unroll
  for (int j = 0; j < 4; ++j) {
    const int col = n0 + wc + j*16 + cl;
    const float bj = bias[col];
    #pragma unroll
    for (int i = 0; i < 4; ++i) {
      const int row = m0 + wr + i*16 + rl;
      #pragma unroll
      for (int r = 0; r < 4; ++r)
        C[(size_t)(row + r) * E_ + col] = acc[i][j][r] + bj;
    }
  }
}

// ---------------- causal GQA flash attention (v16: v8 engine + defer-max T13) -----
// grid (16, 32): x = bh = b*8+h, y = pair j. Block = 4 waves = the 4 query heads
// sharing (b,h)'s K/V, LDS-staged double-buffered (v8-verified). Softmax uses
// DEFER-MAX: lane-local 15-op fmax tree; full 2-shuffle reduce + rescale ONLY
// when !__all(lm <= m + 16.0) (score units; first tile auto-triggers since
// m = -1e30). Deferred P bounded by exp2(K2*16) ~ 7.4 (bf16-safe); l,O in fp32.
// Branch is wave-uniform (__all) -> no divergence.
__global__ __launch_bounds__(256, 2) void attn_kernel(
    const unsigned short* __restrict__ Q, const unsigned short* __restrict__ K,
    const unsigned short* __restrict__ Vt, unsigned short* __restrict__ O)
{
  __shared__ __align__(16) unsigned short Kbuf[2][4096];   // [64 kv][64 d] swizzled
  __shared__ __align__(16) unsigned short Vbuf[2][4096];   // [64 d][64 kv] swizzled
  __shared__ __align__(16) unsigned short Ps[4][2048];     // per-wave P
  const int tid  = threadIdx.x;
  const int w    = tid >> 6;
  const int lane = tid & 63;
  const int bh   = blockIdx.x;      // b*8 + h
  const int b    = bh >> 3;
  const int h    = bh & 7;
  const int j    = blockIdx.y;      // 0..31
  const int hq   = h*4 + w;         // this wave's query head
  const int cl   = lane & 15;
  const int kgrp = lane >> 4;
  const int rl   = kgrp << 2;
  const int li   = lane >> 3;       // 0..7 (staging row-in-group)
  const int lx   = lane & 7;        // 0..7 (staging chunk)

  const float K2  = 0.125f * 1.44269504088896340736f;  // SCALE * log2(e)
  const float THR = 16.0f;                              // defer-max bound (score units)

  char* pws = (char*)&Ps[w][0];
  const unsigned swz = ((unsigned)(cl & 7)) << 4;

  bf16x8 ones8;
  #pragma unroll
  for (int q = 0; q < 8; ++q) ones8[q] = (short)0x3F80;   // bf16 1.0

  const char* Kp = (const char*)(K + (size_t)(b*N_)*512 + h*64);
  const char* Vp = (const char*)(Vt + (size_t)(h*64)*BN_ + b*N_);

  // staging constants: instr i covers rows i*8+li; global chunk = (lx^li)
  const unsigned schunk = ((unsigned)(lx ^ li)) << 4;
  const unsigned kso  = (unsigned)li*1024u + schunk;   // + i*8192  + t*65536
  const unsigned vso  = (unsigned)li*8192u + schunk;   // + i*65536 + t*128
  const unsigned ldst = (unsigned)lane*16u;            // + i*1024

  // fragment read offsets: row z*16+cl, chunk (ks*4+kgrp)^(cl&7)
  unsigned rdo[4][2];
  #pragma unroll
  for (int z = 0; z < 4; ++z)
    #pragma unroll
    for (int ks = 0; ks < 2; ++ks)
      rdo[z][ks] = (unsigned)z*2048u + (unsigned)cl*128u
                 + ((((unsigned)ks*4u + (unsigned)kgrp) ^ (unsigned)(cl & 7)) << 4);

  // P LDS offsets: write b64 (4 kv), read b128 (8 kv)
  unsigned wb[2][4], rb[2][2];
  #pragma unroll
  for (int i = 0; i < 2; ++i) {
    #pragma unroll
    for (int c = 0; c < 4; ++c)
      wb[i][c] = (unsigned)i*2048u + (unsigned)cl*128u
               + (((unsigned)c*32u + (unsigned)kgrp*8u) ^ swz);
    #pragma unroll
    for (int ks = 0; ks < 2; ++ks)
      rb[i][ks] = (unsigned)i*2048u + (unsigned)cl*128u
                + (((unsigned)ks*64u + (unsigned)kgrp*16u) ^ swz);
  }

  for (int sp = 0; sp < 2; ++sp) {
    __syncthreads();   // protect LDS buffers from previous strip
    const int sidx = sp ? (63 - j) : j;
    const int q0   = sidx << 5;
    const int nt   = (sidx >> 1) + 1;   // kv tiles of 64

    // Q fragments (B-operand): lane cl = q row
    bf16x8 qf[2][2];
    #pragma unroll
    for (int i = 0; i < 2; ++i) {
      const size_t qoff = (size_t)(b*N_ + q0 + i*16 + cl) * E_ + hq*64 + (kgrp << 3);
      qf[i][0] = *reinterpret_cast<const bf16x8*>(Q + qoff);
      qf[i][1] = *reinterpret_cast<const bf16x8*>(Q + qoff + 32);
    }

    f32x4 o[2][4] = {};
    f32x4 l4[2] = {};
    float m[2] = {-1e30f, -1e30f};

    // stage tile 0 into buffer 0 (each wave: 2 K + 2 V instructions)
    #pragma unroll
    for (int q = 0; q < 2; ++q) {
      const unsigned i = (unsigned)(w*2 + q);
      gload_lds16(Kp + (i*8192u + kso),  (char*)Kbuf[0] + (i*1024u + ldst));
      gload_lds16(Vp + (i*65536u + vso), (char*)Vbuf[0] + (i*1024u + ldst));
    }
    int cur = 0;
    __syncthreads();   // drain stage

    for (int t = 0; t < nt; ++t) {
      // ---- stage tile t+1 into other buffer (overlaps with compute below) ----
      if (t + 1 < nt) {
        const unsigned kt = (unsigned)(t + 1) * 65536u;
        const unsigned vt = (unsigned)(t + 1) * 128u;
        #pragma unroll
        for (int q = 0; q < 2; ++q) {
          const unsigned i = (unsigned)(w*2 + q);
          gload_lds16(Kp + (kt + i*8192u + kso),  (char*)Kbuf[cur^1] + (i*1024u + ldst));
          gload_lds16(Vp + (vt + i*65536u + vso), (char*)Vbuf[cur^1] + (i*1024u + ldst));
        }
      }

      // ---- K fragments from LDS ----
      bf16x8 kf[4][2];
      #pragma unroll
      for (int c = 0; c < 4; ++c)
        #pragma unroll
        for (int ks = 0; ks < 2; ++ks)
          kf[c][ks] = *reinterpret_cast<const bf16x8*>((const char*)Kbuf[cur] + rdo[c][ks]);

      // ---- S^T = K Q ----
      f32x4 s[2][4];
      #pragma unroll
      for (int i = 0; i < 2; ++i)
        #pragma unroll
        for (int c = 0; c < 4; ++c) {
          f32x4 z = {};
          z = MFMA16(kf[c][0], qf[i][0], z);
          z = MFMA16(kf[c][1], qf[i][1], z);
          s[i][c] = z;
        }

      // ---- causal mask (last tile only): kv > q -> -inf ----
      if (t == nt - 1) {
        const int kvb = t << 6;
        #pragma unroll
        for (int i = 0; i < 2; ++i) {
          const int qq = q0 + i*16 + cl;
          #pragma unroll
          for (int c = 0; c < 4; ++c)
            #pragma unroll
            for (int r = 0; r < 4; ++r)
              if (kvb + c*16 + rl + r > qq) s[i][c][r] = -1e30f;
        }
      }

      // ---- softmax per i-block: DEFER-MAX (T13) ----
      #pragma unroll
      for (int i = 0; i < 2; ++i) {
        float t0 = fmaxf(fmaxf(s[i][0][0], s[i][0][1]), fmaxf(s[i][0][2], s[i][0][3]));
        float t1 = fmaxf(fmaxf(s[i][1][0], s[i][1][1]), fmaxf(s[i][1][2], s[i][1][3]));
        float t2 = fmaxf(fmaxf(s[i][2][0], s[i][2][1]), fmaxf(s[i][2][2], s[i][2][3]));
        float t3 = fmaxf(fmaxf(s[i][3][0], s[i][3][1]), fmaxf(s[i][3][2], s[i][3][3]));
        const float lm = fmaxf(fmaxf(t0, t1), fmaxf(t2, t3));  // lane-local partial max
        if (!__all(lm <= m[i] + THR)) {
          // rare path (first tile + occasional growth): exact reduce + rescale
          float tm = lm;
          tm = fmaxf(tm, __shfl_xor(tm, 16, 64));
          tm = fmaxf(tm, __shfl_xor(tm, 32, 64));
          const float mn = fmaxf(m[i], tm);
          const float al = __builtin_amdgcn_exp2f(K2 * (m[i] - mn));
          m[i] = mn;
          l4[i] *= al;
          #pragma unroll
          for (int db = 0; db < 4; ++db) o[i][db] *= al;
        }
        const float mn = m[i];
        #pragma unroll
        for (int c = 0; c < 4; ++c) {
          ushort4 u;
          u.x = f2bf(__builtin_amdgcn_exp2f(K2 * (s[i][c][0] - mn)));
          u.y = f2bf(__builtin_amdgcn_exp2f(K2 * (s[i][c][1] - mn)));
          u.z = f2bf(__builtin_amdgcn_exp2f(K2 * (s[i][c][2] - mn)));
          u.w = f2bf(__builtin_amdgcn_exp2f(K2 * (s[i][c][3] - mn)));
          *reinterpret_cast<ushort4*>(pws + wb[i][c]) = u;
        }
      }

      // ---- V fragments from LDS ----
      bf16x8 vf[4][2];
      #pragma unroll
      for (int db = 0; db < 4; ++db)
        #pragma unroll
        for (int ks = 0; ks < 2; ++ks)
          vf[db][ks] = *reinterpret_cast<const bf16x8*>((const char*)Vbuf[cur] + rdo[db][ks]);

      // ---- O^T += V^T P ; l += 1 . P ----
      #pragma unroll
      for (int i = 0; i < 2; ++i) {
        const bf16x8 pa0 = *reinterpret_cast<const bf16x8*>(pws + rb[i][0]);
        const bf16x8 pa1 = *reinterpret_cast<const bf16x8*>(pws + rb[i][1]);
        l4[i] = MFMA16(ones8, pa0, l4[i]);
        l4[i] = MFMA16(ones8, pa1, l4[i]);
        #pragma unroll
        for (int db = 0; db < 4; ++db) {
          o[i][db] = MFMA16(vf[db][0], pa0, o[i][db]);
          o[i][db] = MFMA16(vf[db][1], pa1, o[i][db]);
        }
      }

      __syncthreads();   // stage(t+1) drained + all waves done reading buf[cur]
      cur ^= 1;
    }

    // ---- epilogue: O[q][hq*64 + d] = o/l (contiguous ushort4 per (i,db)) ----
    #pragma unroll
    for (int i = 0; i < 2; ++i) {
      const float inv = 1.0f / l4[i][0];
      const size_t orow = (size_t)(b*N_ + q0 + i*16 + cl) * E_ + hq*64 + rl;
      #pragma unroll
      for (int db = 0; db < 4; ++db) {
        ushort4 u;
        u.x = f2bf(o[i][db][0] * inv);
        u.y = f2bf(o[i][db][1] * inv);
        u.z = f2bf(o[i][db][2] * inv);
        u.w = f2bf(o[i][db][3] * inv);
        *reinterpret_cast<ushort4*>(&O[orow + db*16]) = u;
      }
    }
  }
}

extern "C" void kernel_launch(void* const* d_in, const int* in_sizes, int n_in,
                              void* d_out, int out_size, void* d_ws, size_t ws_size,
                              hipStream_t stream) {
  const float* x  = (const float*)d_in[0];
  const float* Wq = (const float*)d_in[1];
  const float* bq = (const float*)d_in[2];
  const float* Wk = (const float*)d_in[3];
  const float* bk = (const float*)d_in[4];
  const float* Wv = (const float*)d_in[5];
  const float* bv = (const float*)d_in[6];
  const float* Wo = (const float*)d_in[7];
  const float* bo = (const float*)d_in[8];
  float* out = (float*)d_out;

  // workspace carve (bf16 elements); cast destinations contiguous in input order
  unsigned short* ws  = (unsigned short*)d_ws;
  unsigned short* xb  = ws;              // 4096x2048
  unsigned short* Wqb = xb  + 8388608;   // 2048x2048
  unsigned short* Wkb = Wqb + 4194304;   // 512x2048
  unsigned short* Wvb = Wkb + 1048576;   // 512x2048
  unsigned short* Wob = Wvb + 1048576;   // 2048x2048
  unsigned short* Qb  = Wob + 4194304;   // 4096x2048
  unsigned short* Kb  = Qb  + 8388608;   // 4096x512
  unsigned short* Vtb = Kb  + 2097152;   // 512x4096 (V transposed)
  unsigned short* Ob  = Vtb + 2097152;   // 4096x2048

  cast_all<<<dim3(2048), dim3(256), 0, stream>>>(x, Wq, Wk, Wv, Wo, xb);

  gemm_qkv<<<dim3(512), dim3(512), 0, stream>>>(xb, Wqb, Wkb, Wvb,
                                                bq, bk, bv, Qb, Kb, Vtb);

  attn_kernel<<<dim3(16, 32), dim3(256), 0, stream>>>(Qb, Kb, Vtb, Ob);

  gemm_out<<<dim3(32*16), dim3(256), 0, stream>>>(Ob, Wob, bo, out);
}

// Round 18
// 172.113 us; speedup vs baseline: 1.1882x; 1.0241x over previous
//
#include <hip/hip_runtime.h>
#include <hip/hip_bf16.h>

// FlashMultiHeadAttention: x -> QKV proj -> causal GQA flash attn -> out proj
// B=2 N=2048 E=2048 HQ=32 HKV=8 D=64 G=4. All compute in bf16 MFMA, fp32 accum.

#define B_   2
#define N_   2048
#define E_   2048
#define HQ_  32
#define HKV_ 8
#define D_   64
#define BN_  (B_*N_)   // 4096 total rows

typedef __attribute__((ext_vector_type(8))) short bf16x8;
typedef __attribute__((ext_vector_type(4))) float f32x4;

#define MFMA16(a,b,c) __builtin_amdgcn_mfma_f32_16x16x32_bf16(a,b,c,0,0,0)

__device__ inline unsigned short f2bf(float f) {
  unsigned u = __builtin_bit_cast(unsigned, f);
  u += 0x7FFFu + ((u >> 16) & 1u);   // RNE
  return (unsigned short)(u >> 16);
}

// pack two f32 -> two truncated bf16 in one v_perm_b32 (P >= 0 so trunc = floor;
// <= 1 ulp (2^-8 rel) vs RNE, bias cancels in O/l). NOTE: v_cvt_pk_bf16_f32
// inline asm produced corrupt results on this toolchain (rounds 6 & 17) - do
// not reintroduce it.
__device__ inline unsigned pack_bf16_trunc(float lo, float hi) {
  return __builtin_amdgcn_perm(__builtin_bit_cast(unsigned, hi),
                               __builtin_bit_cast(unsigned, lo), 0x07060302u);
}

__device__ inline void gload_lds16(const void* g, void* l) {
  __builtin_amdgcn_global_load_lds(
      (const __attribute__((address_space(1))) void*)g,
      (__attribute__((address_space(3))) void*)l, 16, 0, 0);
}

// ---------------- fused cast fp32 -> bf16 for x,Wq,Wk,Wv,Wo ----------------
__global__ void cast_all(const float* __restrict__ x,  const float* __restrict__ wq,
                         const float* __restrict__ wk, const float* __restrict__ wv,
                         const float* __restrict__ wo, unsigned short* __restrict__ dst) {
  const int c0 = 2097152;            // x      (8388608 elems /4)
  const int c1 = c0 + 1048576;       // Wq
  const int c2 = c1 + 262144;        // Wk
  const int c3 = c2 + 262144;        // Wv
  const int c4 = c3 + 1048576;       // Wo
  int i = blockIdx.x * blockDim.x + threadIdx.x;
  const int stride = gridDim.x * blockDim.x;
  for (; i < c4; i += stride) {
    const float* src; int off;
    if      (i < c0) { src = x;  off = i; }
    else if (i < c1) { src = wq; off = i - c0; }
    else if (i < c2) { src = wk; off = i - c1; }
    else if (i < c3) { src = wv; off = i - c2; }
    else             { src = wo; off = i - c3; }
    float4 f = reinterpret_cast<const float4*>(src)[off];
    ushort4 u;
    u.x = f2bf(f.x); u.y = f2bf(f.y); u.z = f2bf(f.z); u.w = f2bf(f.w);
    reinterpret_cast<ushort4*>(dst)[i] = u;
  }
}

// ---------------- fused QKV projection GEMM: 128x192 tile, EXACT 2-blocks/CU ------
// (v15-verified) BM=128, BN=192 (virtual QKV cols 3072 = 16 x 192), BK=64.
// Grid 512 = exactly 2 per CU. 8 waves (2M x 4N), per-wave 64x48 (acc[4][3]).
// LDS dbuf: As[2][128x64] + Bs[2][192x64] = 80KB. Thin counted-vmcnt schedule.
__global__ __launch_bounds__(512, 4) void gemm_qkv(
    const unsigned short* __restrict__ A,
    const unsigned short* __restrict__ Wq, const unsigned short* __restrict__ Wk,
    const unsigned short* __restrict__ Wv,
    const float* __restrict__ bq, const float* __restrict__ bk, const float* __restrict__ bv,
    unsigned short* __restrict__ Qo, unsigned short* __restrict__ Ko,
    unsigned short* __restrict__ Vto)
{
  __shared__ __align__(16) unsigned short As[2][8192];    // [buf][128*64]  2x16KB
  __shared__ __align__(16) unsigned short Bs[2][12288];   // [buf][192*64]  2x24KB
  const int tid  = threadIdx.x;
  const int w    = tid >> 6;
  const int lane = tid & 63;
  const int g    = blockIdx.x & 7;        // XCD slot
  const int s    = blockIdx.x >> 3;       // 0..63
  const int bm   = g*4 + (s >> 4);        // 0..31 (4 bm-panels per XCD)
  const int bn   = s & 15;                // 0..15
  const int m0   = bm << 7;
  const int n0v  = bn * 192;              // virtual col in [Q|K|V] = 3072
  const int K    = E_;

  const int mgrp = w >> 2;                // 0/1: rows mgrp*64
  const int ngrp = w & 3;                 // cols ngrp*48
  const int cl   = lane & 15;
  const int kgrp = lane >> 4;
  const int rl   = kgrp << 2;
  const int li   = lane >> 3;             // staging row-in-group 0..7
  const int lx   = lane & 7;              // staging chunk 0..7

  // staging bases; global chunk = lx^li (inverse swizzle)
  const unsigned gsw = ((unsigned)(lx ^ li)) << 3;   // elems
  const unsigned short* gA = A + (size_t)(m0 + w*16 + li) * K + gsw;
  const unsigned short* gBq[3];
  #pragma unroll
  for (int q = 0; q < 3; ++q) {
    const int vr = n0v + w*24 + q*8;      // seg-uniform (2048/2560 % 8 == 0)
    const unsigned short* base;
    if (vr < 2048)      base = Wq + (size_t)vr * K;
    else if (vr < 2560) base = Wk + (size_t)(vr - 2048) * K;
    else                base = Wv + (size_t)(vr - 2560) * K;
    gBq[q] = base + (size_t)li * K + gsw;
  }
  const unsigned aDst = (unsigned)(w*16)*64u + (unsigned)lane*8u;  // elems
  const unsigned bDst = (unsigned)(w*24)*64u + (unsigned)lane*8u;

  // read offsets (elems): row*64 + ((ks*4+kgrp)^(cl&7))*8
  unsigned rAo[4][2], rBo[3][2];
  #pragma unroll
  for (int ks = 0; ks < 2; ++ks) {
    const unsigned c8 = (((unsigned)(ks*4 + kgrp)) ^ (unsigned)(cl & 7)) << 3;
    #pragma unroll
    for (int z = 0; z < 4; ++z)
      rAo[z][ks] = (unsigned)(mgrp*64 + z*16 + cl) * 64u + c8;
    #pragma unroll
    for (int jj = 0; jj < 3; ++jj)
      rBo[jj][ks] = (unsigned)(ngrp*48 + jj*16 + cl) * 64u + c8;
  }

  f32x4 acc[4][3] = {};
  const int nt = K >> 6;   // 32

  auto STAGE = [&](int kt, int buf) {   // 5 wave-loads: 2 A + 3 B
    const int ko = kt << 6;
    #pragma unroll
    for (int q = 0; q < 2; ++q)
      gload_lds16(gA + (size_t)(q*8)*K + ko, &As[buf][aDst + q*512u]);
    #pragma unroll
    for (int q = 0; q < 3; ++q)
      gload_lds16(gBq[q] + ko, &Bs[buf][bDst + q*512u]);
  };

  STAGE(0, 0);
  int p = 0;

  for (int t = 0; t < nt; ++t) {
    if (t + 1 < nt) {
      STAGE(t + 1, p ^ 1);
      asm volatile("s_waitcnt vmcnt(5)" ::: "memory");   // tile-t landed
    } else {
      asm volatile("s_waitcnt vmcnt(0)" ::: "memory");
    }
    __builtin_amdgcn_s_barrier();
    #pragma unroll
    for (int ks = 0; ks < 2; ++ks) {
      bf16x8 af[4], bfr[3];
      #pragma unroll
      for (int z = 0; z < 4; ++z)
        af[z] = *reinterpret_cast<const bf16x8*>(&As[p][rAo[z][ks]]);
      #pragma unroll
      for (int jj = 0; jj < 3; ++jj)
        bfr[jj] = *reinterpret_cast<const bf16x8*>(&Bs[p][rBo[jj][ks]]);
      __builtin_amdgcn_s_setprio(1);
      #pragma unroll
      for (int z = 0; z < 4; ++z)
        #pragma unroll
        for (int jj = 0; jj < 3; ++jj)
          acc[z][jj] = MFMA16(af[z], bfr[jj], acc[z][jj]);
      __builtin_amdgcn_s_setprio(0);
    }
    __builtin_amdgcn_s_barrier();   // reads consumed -> safe to restage buf p
    p ^= 1;
  }

  // epilogue: per-(jj) 16-col fragment is segment-uniform (2048/2560 % 16 == 0)
  #pragma unroll
  for (int z = 0; z < 4; ++z) {
    const int rowb = m0 + mgrp*64 + z*16 + rl;
    #pragma unroll
    for (int jj = 0; jj < 3; ++jj) {
      const int col16 = n0v + ngrp*48 + jj*16;
      if (col16 < 2048) {
        const int col = col16 + cl;
        const float bj = bq[col];
        #pragma unroll
        for (int r = 0; r < 4; ++r)
          Qo[(size_t)(rowb + r) * 2048 + col] = f2bf(acc[z][jj][r] + bj);
      } else if (col16 < 2560) {
        const int col = col16 - 2048 + cl;
        const float bj = bk[col];
        #pragma unroll
        for (int r = 0; r < 4; ++r)
          Ko[(size_t)(rowb + r) * 512 + col] = f2bf(acc[z][jj][r] + bj);
      } else {
        const int col = col16 - 2560 + cl;
        const float bj = bv[col];
        ushort4 u;
        u.x = f2bf(acc[z][jj][0] + bj);
        u.y = f2bf(acc[z][jj][1] + bj);
        u.z = f2bf(acc[z][jj][2] + bj);
        u.w = f2bf(acc[z][jj][3] + bj);
        *reinterpret_cast<ushort4*>(&Vto[(size_t)col * 4096 + rowb]) = u;
      }
    }
  }
}

// ---------------- out-proj GEMM (v9 engine: BK=64 single-buffer, fp32 out) --------
__global__ __launch_bounds__(256) void gemm_out(
    const unsigned short* __restrict__ A, const unsigned short* __restrict__ W,
    const float* __restrict__ bias, float* __restrict__ C)
{
  __shared__ __align__(16) unsigned short As[128*64];
  __shared__ __align__(16) unsigned short Bs[128*64];
  const int tid  = threadIdx.x;
  const int w    = tid >> 6;
  const int lane = tid & 63;
  const int bm   = blockIdx.x >> 4;
  const int bn   = blockIdx.x & 15;
  const int m0   = bm << 7, n0 = bn << 7;
  const int K    = E_;
  const int wr   = (w >> 1) << 6;
  const int wc   = (w & 1) << 6;
  const int cl   = lane & 15;
  const int kgrp = lane >> 4;
  const int rl   = kgrp << 2;
  const int li   = lane >> 3;
  const int lx   = lane & 7;

  const unsigned schunk = ((unsigned)(lx ^ li)) << 3;
  const unsigned short* gA = A + (size_t)(m0 + li) * K + schunk;
  const unsigned short* gB = W + (size_t)(n0 + li) * K + schunk;
  unsigned short* lA = As + lane*8;
  unsigned short* lB = Bs + lane*8;

  unsigned rA[4][2], rB[4][2];
  #pragma unroll
  for (int z = 0; z < 4; ++z)
    #pragma unroll
    for (int ks = 0; ks < 2; ++ks) {
      rA[z][ks] = (unsigned)(wr + z*16 + cl)*64u + ((((unsigned)ks*4u + (unsigned)kgrp) ^ (unsigned)(cl & 7)) << 3);
      rB[z][ks] = (unsigned)(wc + z*16 + cl)*64u + ((((unsigned)ks*4u + (unsigned)kgrp) ^ (unsigned)(cl & 7)) << 3);
    }

  f32x4 acc[4][4] = {};

  for (int kt = 0; kt < (K >> 6); ++kt) {
    const int ko = kt << 6;
    #pragma unroll
    for (int q = 0; q < 4; ++q) {
      const unsigned i = (unsigned)(w*4 + q);
      gload_lds16(gA + ((size_t)i*8*K + ko), lA + i*512);
      gload_lds16(gB + ((size_t)i*8*K + ko), lB + i*512);
    }
    __syncthreads();
    #pragma unroll
    for (int ks = 0; ks < 2; ++ks) {
      bf16x8 af[4], bfr[4];
      #pragma unroll
      for (int i = 0; i < 4; ++i)
        af[i] = *reinterpret_cast<const bf16x8*>(&As[rA[i][ks]]);
      #pragma unroll
      for (int j = 0; j < 4; ++j)
        bfr[j] = *reinterpret_cast<const bf16x8*>(&Bs[rB[j][ks]]);
      #pragma unroll
      for (int i = 0; i < 4; ++i)
        #pragma unroll
        for (int j = 0; j < 4; ++j)
          acc[i][j] = MFMA16(af[i], bfr[j], acc[i][j]);
    }
    __syncthreads();
  }

  #pragma unroll
  for (int j = 0; j < 4; ++j) {
    const int col = n0 + wc + j*16 + cl;
    const float bj = bias[col];
    #pragma unroll
    for (int i = 0; i < 4; ++i) {
      const int row = m0 + wr + i*16 + rl;
      #pragma unroll
      for (int r = 0; r < 4; ++r)
        C[(size_t)(row + r) * E_ + col] = acc[i][j][r] + bj;
    }
  }
}

// ---------------- causal GQA flash attention (v18: v16 + v_perm P-pack) -----------
// grid (16, 32): x = bh = b*8+h, y = pair j. Block = 4 waves = the 4 query heads
// sharing (b,h)'s K/V, LDS-staged double-buffered (v8-verified). Defer-max
// softmax (v16-verified). P-pack uses __builtin_amdgcn_perm (1 op packs 2
// truncated bf16) instead of 4-op manual f2bf per elem; O epilogue keeps RNE.
__global__ __launch_bounds__(256, 2) void attn_kernel(
    const unsigned short* __restrict__ Q, const unsigned short* __restrict__ K,
    const unsigned short* __restrict__ Vt, unsigned short* __restrict__ O)
{
  __shared__ __align__(16) unsigned short Kbuf[2][4096];   // [64 kv][64 d] swizzled
  __shared__ __align__(16) unsigned short Vbuf[2][4096];   // [64 d][64 kv] swizzled
  __shared__ __align__(16) unsigned short Ps[4][2048];     // per-wave P
  const int tid  = threadIdx.x;
  const int w    = tid >> 6;
  const int lane = tid & 63;
  const int bh   = blockIdx.x;      // b*8 + h
  const int b    = bh >> 3;
  const int h    = bh & 7;
  const int j    = blockIdx.y;      // 0..31
  const int hq   = h*4 + w;         // this wave's query head
  const int cl   = lane & 15;
  const int kgrp = lane >> 4;
  const int rl   = kgrp << 2;
  const int li   = lane >> 3;       // 0..7 (staging row-in-group)
  const int lx   = lane & 7;        // 0..7 (staging chunk)

  const float K2  = 0.125f * 1.44269504088896340736f;  // SCALE * log2(e)
  const float THR = 16.0f;                              // defer-max bound (score units)

  char* pws = (char*)&Ps[w][0];
  const unsigned swz = ((unsigned)(cl & 7)) << 4;

  bf16x8 ones8;
  #pragma unroll
  for (int q = 0; q < 8; ++q) ones8[q] = (short)0x3F80;   // bf16 1.0

  const char* Kp = (const char*)(K + (size_t)(b*N_)*512 + h*64);
  const char* Vp = (const char*)(Vt + (size_t)(h*64)*BN_ + b*N_);

  // staging constants: instr i covers rows i*8+li; global chunk = (lx^li)
  const unsigned schunk = ((unsigned)(lx ^ li)) << 4;
  const unsigned kso  = (unsigned)li*1024u + schunk;   // + i*8192  + t*65536
  const unsigned vso  = (unsigned)li*8192u + schunk;   // + i*65536 + t*128
  const unsigned ldst = (unsigned)lane*16u;            // + i*1024

  // fragment read offsets: row z*16+cl, chunk (ks*4+kgrp)^(cl&7)
  unsigned rdo[4][2];
  #pragma unroll
  for (int z = 0; z < 4; ++z)
    #pragma unroll
    for (int ks = 0; ks < 2; ++ks)
      rdo[z][ks] = (unsigned)z*2048u + (unsigned)cl*128u
                 + ((((unsigned)ks*4u + (unsigned)kgrp) ^ (unsigned)(cl & 7)) << 4);

  // P LDS offsets: write b64 (4 kv), read b128 (8 kv)
  unsigned wb[2][4], rb[2][2];
  #pragma unroll
  for (int i = 0; i < 2; ++i) {
    #pragma unroll
    for (int c = 0; c < 4; ++c)
      wb[i][c] = (unsigned)i*2048u + (unsigned)cl*128u
               + (((unsigned)c*32u + (unsigned)kgrp*8u) ^ swz);
    #pragma unroll
    for (int ks = 0; ks < 2; ++ks)
      rb[i][ks] = (unsigned)i*2048u + (unsigned)cl*128u
                + (((unsigned)ks*64u + (unsigned)kgrp*16u) ^ swz);
  }

  for (int sp = 0; sp < 2; ++sp) {
    __syncthreads();   // protect LDS buffers from previous strip
    const int sidx = sp ? (63 - j) : j;
    const int q0   = sidx << 5;
    const int nt   = (sidx >> 1) + 1;   // kv tiles of 64

    // Q fragments (B-operand): lane cl = q row
    bf16x8 qf[2][2];
    #pragma unroll
    for (int i = 0; i < 2; ++i) {
      const size_t qoff = (size_t)(b*N_ + q0 + i*16 + cl) * E_ + hq*64 + (kgrp << 3);
      qf[i][0] = *reinterpret_cast<const bf16x8*>(Q + qoff);
      qf[i][1] = *reinterpret_cast<const bf16x8*>(Q + qoff + 32);
    }

    f32x4 o[2][4] = {};
    f32x4 l4[2] = {};
    float m[2] = {-1e30f, -1e30f};

    // stage tile 0 into buffer 0 (each wave: 2 K + 2 V instructions)
    #pragma unroll
    for (int q = 0; q < 2; ++q) {
      const unsigned i = (unsigned)(w*2 + q);
      gload_lds16(Kp + (i*8192u + kso),  (char*)Kbuf[0] + (i*1024u + ldst));
      gload_lds16(Vp + (i*65536u + vso), (char*)Vbuf[0] + (i*1024u + ldst));
    }
    int cur = 0;
    __syncthreads();   // drain stage

    for (int t = 0; t < nt; ++t) {
      // ---- stage tile t+1 into other buffer (overlaps with compute below) ----
      if (t + 1 < nt) {
        const unsigned kt = (unsigned)(t + 1) * 65536u;
        const unsigned vt = (unsigned)(t + 1) * 128u;
        #pragma unroll
        for (int q = 0; q < 2; ++q) {
          const unsigned i = (unsigned)(w*2 + q);
          gload_lds16(Kp + (kt + i*8192u + kso),  (char*)Kbuf[cur^1] + (i*1024u + ldst));
          gload_lds16(Vp + (vt + i*65536u + vso), (char*)Vbuf[cur^1] + (i*1024u + ldst));
        }
      }

      // ---- K fragments from LDS ----
      bf16x8 kf[4][2];
      #pragma unroll
      for (int c = 0; c < 4; ++c)
        #pragma unroll
        for (int ks = 0; ks < 2; ++ks)
          kf[c][ks] = *reinterpret_cast<const bf16x8*>((const char*)Kbuf[cur] + rdo[c][ks]);

      // ---- S^T = K Q ----
      f32x4 s[2][4];
      #pragma unroll
      for (int i = 0; i < 2; ++i)
        #pragma unroll
        for (int c = 0; c < 4; ++c) {
          f32x4 z = {};
          z = MFMA16(kf[c][0], qf[i][0], z);
          z = MFMA16(kf[c][1], qf[i][1], z);
          s[i][c] = z;
        }

      // ---- causal mask (last tile only): kv > q -> -inf ----
      if (t == nt - 1) {
        const int kvb = t << 6;
        #pragma unroll
        for (int i = 0; i < 2; ++i) {
          const int qq = q0 + i*16 + cl;
          #pragma unroll
          for (int c = 0; c < 4; ++c)
            #pragma unroll
            for (int r = 0; r < 4; ++r)
              if (kvb + c*16 + rl + r > qq) s[i][c][r] = -1e30f;
        }
      }

      // ---- softmax per i-block: DEFER-MAX (T13) + v_perm P-pack ----
      #pragma unroll
      for (int i = 0; i < 2; ++i) {
        float t0 = fmaxf(fmaxf(s[i][0][0], s[i][0][1]), fmaxf(s[i][0][2], s[i][0][3]));
        float t1 = fmaxf(fmaxf(s[i][1][0], s[i][1][1]), fmaxf(s[i][1][2], s[i][1][3]));
        float t2 = fmaxf(fmaxf(s[i][2][0], s[i][2][1]), fmaxf(s[i][2][2], s[i][2][3]));
        float t3 = fmaxf(fmaxf(s[i][3][0], s[i][3][1]), fmaxf(s[i][3][2], s[i][3][3]));
        const float lm = fmaxf(fmaxf(t0, t1), fmaxf(t2, t3));  // lane-local partial max
        if (!__all(lm <= m[i] + THR)) {
          // rare path (first tile + occasional growth): exact reduce + rescale
          float tm = lm;
          tm = fmaxf(tm, __shfl_xor(tm, 16, 64));
          tm = fmaxf(tm, __shfl_xor(tm, 32, 64));
          const float mn = fmaxf(m[i], tm);
          const float al = __builtin_amdgcn_exp2f(K2 * (m[i] - mn));
          m[i] = mn;
          l4[i] *= al;
          #pragma unroll
          for (int db = 0; db < 4; ++db) o[i][db] *= al;
        }
        const float mn = m[i];
        #pragma unroll
        for (int c = 0; c < 4; ++c) {
          const float e0 = __builtin_amdgcn_exp2f(K2 * (s[i][c][0] - mn));
          const float e1 = __builtin_amdgcn_exp2f(K2 * (s[i][c][1] - mn));
          const float e2 = __builtin_amdgcn_exp2f(K2 * (s[i][c][2] - mn));
          const float e3 = __builtin_amdgcn_exp2f(K2 * (s[i][c][3] - mn));
          uint2 u;
          u.x = pack_bf16_trunc(e0, e1);
          u.y = pack_bf16_trunc(e2, e3);
          *reinterpret_cast<uint2*>(pws + wb[i][c]) = u;
        }
      }

      // ---- V fragments from LDS ----
      bf16x8 vf[4][2];
      #pragma unroll
      for (int db = 0; db < 4; ++db)
        #pragma unroll
        for (int ks = 0; ks < 2; ++ks)
          vf[db][ks] = *reinterpret_cast<const bf16x8*>((const char*)Vbuf[cur] + rdo[db][ks]);

      // ---- O^T += V^T P ; l += 1 . P ----
      #pragma unroll
      for (int i = 0; i < 2; ++i) {
        const bf16x8 pa0 = *reinterpret_cast<const bf16x8*>(pws + rb[i][0]);
        const bf16x8 pa1 = *reinterpret_cast<const bf16x8*>(pws + rb[i][1]);
        l4[i] = MFMA16(ones8, pa0, l4[i]);
        l4[i] = MFMA16(ones8, pa1, l4[i]);
        #pragma unroll
        for (int db = 0; db < 4; ++db) {
          o[i][db] = MFMA16(vf[db][0], pa0, o[i][db]);
          o[i][db] = MFMA16(vf[db][1], pa1, o[i][db]);
        }
      }

      __syncthreads();   // stage(t+1) drained + all waves done reading buf[cur]
      cur ^= 1;
    }

    // ---- epilogue: O[q][hq*64 + d] = o/l (RNE f2bf, 8B stores) ----
    #pragma unroll
    for (int i = 0; i < 2; ++i) {
      const float inv = 1.0f / l4[i][0];
      const size_t orow = (size_t)(b*N_ + q0 + i*16 + cl) * E_ + hq*64 + rl;
      #pragma unroll
      for (int db = 0; db < 4; ++db) {
        ushort4 u;
        u.x = f2bf(o[i][db][0] * inv);
        u.y = f2bf(o[i][db][1] * inv);
        u.z = f2bf(o[i][db][2] * inv);
        u.w = f2bf(o[i][db][3] * inv);
        *reinterpret_cast<ushort4*>(&O[orow + db*16]) = u;
      }
    }
  }
}

extern "C" void kernel_launch(void* const* d_in, const int* in_sizes, int n_in,
                              void* d_out, int out_size, void* d_ws, size_t ws_size,
                              hipStream_t stream) {
  const float* x  = (const float*)d_in[0];
  const float* Wq = (const float*)d_in[1];
  const float* bq = (const float*)d_in[2];
  const float* Wk = (const float*)d_in[3];
  const float* bk = (const float*)d_in[4];
  const float* Wv = (const float*)d_in[5];
  const float* bv = (const float*)d_in[6];
  const float* Wo = (const float*)d_in[7];
  const float* bo = (const float*)d_in[8];
  float* out = (float*)d_out;

  // workspace carve (bf16 elements); cast destinations contiguous in input order
  unsigned short* ws  = (unsigned short*)d_ws;
  unsigned short* xb  = ws;              // 4096x2048
  unsigned short* Wqb = xb  + 8388608;   // 2048x2048
  unsigned short* Wkb = Wqb + 4194304;   // 512x2048
  unsigned short* Wvb = Wkb + 1048576;   // 512x2048
  unsigned short* Wob = Wvb + 1048576;   // 2048x2048
  unsigned short* Qb  = Wob + 4194304;   // 4096x2048
  unsigned short* Kb  = Qb  + 8388608;   // 4096x512
  unsigned short* Vtb = Kb  + 2097152;   // 512x4096 (V transposed)
  unsigned short* Ob  = Vtb + 2097152;   // 4096x2048

  cast_all<<<dim3(2048), dim3(256), 0, stream>>>(x, Wq, Wk, Wv, Wo, xb);

  gemm_qkv<<<dim3(512), dim3(512), 0, stream>>>(xb, Wqb, Wkb, Wvb,
                                                bq, bk, bv, Qb, Kb, Vtb);

  attn_kernel<<<dim3(16, 32), dim3(256), 0, stream>>>(Qb, Kb, Vtb, Ob);

  gemm_out<<<dim3(32*16), dim3(256), 0, stream>>>(Ob, Wob, bo, out);
}

// Round 19
// 167.276 us; speedup vs baseline: 1.2226x; 1.0289x over previous
//
#include <hip/hip_runtime.h>
#include <hip/hip_bf16.h>

// FlashMultiHeadAttention: x -> QKV proj -> causal GQA flash attn -> out proj
// B=2 N=2048 E=2048 HQ=32 HKV=8 D=64 G=4. All compute in bf16 MFMA, fp32 accum.

#define B_   2
#define N_   2048
#define E_   2048
#define HQ_  32
#define HKV_ 8
#define D_   64
#define BN_  (B_*N_)   // 4096 total rows

typedef __attribute__((ext_vector_type(8))) short bf16x8;
typedef __attribute__((ext_vector_type(4))) float f32x4;

#define MFMA16(a,b,c) __builtin_amdgcn_mfma_f32_16x16x32_bf16(a,b,c,0,0,0)

__device__ inline unsigned short f2bf(float f) {
  unsigned u = __builtin_bit_cast(unsigned, f);
  u += 0x7FFFu + ((u >> 16) & 1u);   // RNE
  return (unsigned short)(u >> 16);
}

// pack two f32 -> two truncated bf16 in one v_perm_b32 (P >= 0 so trunc = floor;
// <= 1 ulp (2^-8 rel) vs RNE, bias cancels in O/l). NOTE: v_cvt_pk_bf16_f32
// inline asm produced corrupt results on this toolchain (rounds 6 & 17) - do
// not reintroduce it.
__device__ inline unsigned pack_bf16_trunc(float lo, float hi) {
  return __builtin_amdgcn_perm(__builtin_bit_cast(unsigned, hi),
                               __builtin_bit_cast(unsigned, lo), 0x07060302u);
}

__device__ inline void gload_lds16(const void* g, void* l) {
  __builtin_amdgcn_global_load_lds(
      (const __attribute__((address_space(1))) void*)g,
      (__attribute__((address_space(3))) void*)l, 16, 0, 0);
}

// ---------------- fused cast fp32 -> bf16 for x,Wq,Wk,Wv,Wo ----------------
__global__ void cast_all(const float* __restrict__ x,  const float* __restrict__ wq,
                         const float* __restrict__ wk, const float* __restrict__ wv,
                         const float* __restrict__ wo, unsigned short* __restrict__ dst) {
  const int c0 = 2097152;            // x      (8388608 elems /4)
  const int c1 = c0 + 1048576;       // Wq
  const int c2 = c1 + 262144;        // Wk
  const int c3 = c2 + 262144;        // Wv
  const int c4 = c3 + 1048576;       // Wo
  int i = blockIdx.x * blockDim.x + threadIdx.x;
  const int stride = gridDim.x * blockDim.x;
  for (; i < c4; i += stride) {
    const float* src; int off;
    if      (i < c0) { src = x;  off = i; }
    else if (i < c1) { src = wq; off = i - c0; }
    else if (i < c2) { src = wk; off = i - c1; }
    else if (i < c3) { src = wv; off = i - c2; }
    else             { src = wo; off = i - c3; }
    float4 f = reinterpret_cast<const float4*>(src)[off];
    ushort4 u;
    u.x = f2bf(f.x); u.y = f2bf(f.y); u.z = f2bf(f.z); u.w = f2bf(f.w);
    reinterpret_cast<ushort4*>(dst)[i] = u;
  }
}

// ---------------- fused QKV projection GEMM: 128x192 tile, EXACT 2-blocks/CU ------
// (v15-verified) BM=128, BN=192 (virtual QKV cols 3072 = 16 x 192), BK=64.
// Grid 512 = exactly 2 per CU. 8 waves (2M x 4N), per-wave 64x48 (acc[4][3]).
// LDS dbuf: As[2][128x64] + Bs[2][192x64] = 80KB. Thin counted-vmcnt schedule.
__global__ __launch_bounds__(512, 4) void gemm_qkv(
    const unsigned short* __restrict__ A,
    const unsigned short* __restrict__ Wq, const unsigned short* __restrict__ Wk,
    const unsigned short* __restrict__ Wv,
    const float* __restrict__ bq, const float* __restrict__ bk, const float* __restrict__ bv,
    unsigned short* __restrict__ Qo, unsigned short* __restrict__ Ko,
    unsigned short* __restrict__ Vto)
{
  __shared__ __align__(16) unsigned short As[2][8192];    // [buf][128*64]  2x16KB
  __shared__ __align__(16) unsigned short Bs[2][12288];   // [buf][192*64]  2x24KB
  const int tid  = threadIdx.x;
  const int w    = tid >> 6;
  const int lane = tid & 63;
  const int g    = blockIdx.x & 7;        // XCD slot
  const int s    = blockIdx.x >> 3;       // 0..63
  const int bm   = g*4 + (s >> 4);        // 0..31 (4 bm-panels per XCD)
  const int bn   = s & 15;                // 0..15
  const int m0   = bm << 7;
  const int n0v  = bn * 192;              // virtual col in [Q|K|V] = 3072
  const int K    = E_;

  const int mgrp = w >> 2;                // 0/1: rows mgrp*64
  const int ngrp = w & 3;                 // cols ngrp*48
  const int cl   = lane & 15;
  const int kgrp = lane >> 4;
  const int rl   = kgrp << 2;
  const int li   = lane >> 3;             // staging row-in-group 0..7
  const int lx   = lane & 7;              // staging chunk 0..7

  // staging bases; global chunk = lx^li (inverse swizzle)
  const unsigned gsw = ((unsigned)(lx ^ li)) << 3;   // elems
  const unsigned short* gA = A + (size_t)(m0 + w*16 + li) * K + gsw;
  const unsigned short* gBq[3];
  #pragma unroll
  for (int q = 0; q < 3; ++q) {
    const int vr = n0v + w*24 + q*8;      // seg-uniform (2048/2560 % 8 == 0)
    const unsigned short* base;
    if (vr < 2048)      base = Wq + (size_t)vr * K;
    else if (vr < 2560) base = Wk + (size_t)(vr - 2048) * K;
    else                base = Wv + (size_t)(vr - 2560) * K;
    gBq[q] = base + (size_t)li * K + gsw;
  }
  const unsigned aDst = (unsigned)(w*16)*64u + (unsigned)lane*8u;  // elems
  const unsigned bDst = (unsigned)(w*24)*64u + (unsigned)lane*8u;

  // read offsets (elems): row*64 + ((ks*4+kgrp)^(cl&7))*8
  unsigned rAo[4][2], rBo[3][2];
  #pragma unroll
  for (int ks = 0; ks < 2; ++ks) {
    const unsigned c8 = (((unsigned)(ks*4 + kgrp)) ^ (unsigned)(cl & 7)) << 3;
    #pragma unroll
    for (int z = 0; z < 4; ++z)
      rAo[z][ks] = (unsigned)(mgrp*64 + z*16 + cl) * 64u + c8;
    #pragma unroll
    for (int jj = 0; jj < 3; ++jj)
      rBo[jj][ks] = (unsigned)(ngrp*48 + jj*16 + cl) * 64u + c8;
  }

  f32x4 acc[4][3] = {};
  const int nt = K >> 6;   // 32

  auto STAGE = [&](int kt, int buf) {   // 5 wave-loads: 2 A + 3 B
    const int ko = kt << 6;
    #pragma unroll
    for (int q = 0; q < 2; ++q)
      gload_lds16(gA + (size_t)(q*8)*K + ko, &As[buf][aDst + q*512u]);
    #pragma unroll
    for (int q = 0; q < 3; ++q)
      gload_lds16(gBq[q] + ko, &Bs[buf][bDst + q*512u]);
  };

  STAGE(0, 0);
  int p = 0;

  for (int t = 0; t < nt; ++t) {
    if (t + 1 < nt) {
      STAGE(t + 1, p ^ 1);
      asm volatile("s_waitcnt vmcnt(5)" ::: "memory");   // tile-t landed
    } else {
      asm volatile("s_waitcnt vmcnt(0)" ::: "memory");
    }
    __builtin_amdgcn_s_barrier();
    #pragma unroll
    for (int ks = 0; ks < 2; ++ks) {
      bf16x8 af[4], bfr[3];
      #pragma unroll
      for (int z = 0; z < 4; ++z)
        af[z] = *reinterpret_cast<const bf16x8*>(&As[p][rAo[z][ks]]);
      #pragma unroll
      for (int jj = 0; jj < 3; ++jj)
        bfr[jj] = *reinterpret_cast<const bf16x8*>(&Bs[p][rBo[jj][ks]]);
      __builtin_amdgcn_s_setprio(1);
      #pragma unroll
      for (int z = 0; z < 4; ++z)
        #pragma unroll
        for (int jj = 0; jj < 3; ++jj)
          acc[z][jj] = MFMA16(af[z], bfr[jj], acc[z][jj]);
      __builtin_amdgcn_s_setprio(0);
    }
    __builtin_amdgcn_s_barrier();   // reads consumed -> safe to restage buf p
    p ^= 1;
  }

  // epilogue: per-(jj) 16-col fragment is segment-uniform (2048/2560 % 16 == 0)
  #pragma unroll
  for (int z = 0; z < 4; ++z) {
    const int rowb = m0 + mgrp*64 + z*16 + rl;
    #pragma unroll
    for (int jj = 0; jj < 3; ++jj) {
      const int col16 = n0v + ngrp*48 + jj*16;
      if (col16 < 2048) {
        const int col = col16 + cl;
        const float bj = bq[col];
        #pragma unroll
        for (int r = 0; r < 4; ++r)
          Qo[(size_t)(rowb + r) * 2048 + col] = f2bf(acc[z][jj][r] + bj);
      } else if (col16 < 2560) {
        const int col = col16 - 2048 + cl;
        const float bj = bk[col];
        #pragma unroll
        for (int r = 0; r < 4; ++r)
          Ko[(size_t)(rowb + r) * 512 + col] = f2bf(acc[z][jj][r] + bj);
      } else {
        const int col = col16 - 2560 + cl;
        const float bj = bv[col];
        ushort4 u;
        u.x = f2bf(acc[z][jj][0] + bj);
        u.y = f2bf(acc[z][jj][1] + bj);
        u.z = f2bf(acc[z][jj][2] + bj);
        u.w = f2bf(acc[z][jj][3] + bj);
        *reinterpret_cast<ushort4*>(&Vto[(size_t)col * 4096 + rowb]) = u;
      }
    }
  }
}

// ---------------- out-proj GEMM (v9 engine: BK=64 single-buffer, fp32 out) --------
__global__ __launch_bounds__(256) void gemm_out(
    const unsigned short* __restrict__ A, const unsigned short* __restrict__ W,
    const float* __restrict__ bias, float* __restrict__ C)
{
  __shared__ __align__(16) unsigned short As[128*64];
  __shared__ __align__(16) unsigned short Bs[128*64];
  const int tid  = threadIdx.x;
  const int w    = tid >> 6;
  const int lane = tid & 63;
  const int bm   = blockIdx.x >> 4;
  const int bn   = blockIdx.x & 15;
  const int m0   = bm << 7, n0 = bn << 7;
  const int K    = E_;
  const int wr   = (w >> 1) << 6;
  const int wc   = (w & 1) << 6;
  const int cl   = lane & 15;
  const int kgrp = lane >> 4;
  const int rl   = kgrp << 2;
  const int li   = lane >> 3;
  const int lx   = lane & 7;

  const unsigned schunk = ((unsigned)(lx ^ li)) << 3;
  const unsigned short* gA = A + (size_t)(m0 + li) * K + schunk;
  const unsigned short* gB = W + (size_t)(n0 + li) * K + schunk;
  unsigned short* lA = As + lane*8;
  unsigned short* lB = Bs + lane*8;

  unsigned rA[4][2], rB[4][2];
  #pragma unroll
  for (int z = 0; z < 4; ++z)
    #pragma unroll
    for (int ks = 0; ks < 2; ++ks) {
      rA[z][ks] = (unsigned)(wr + z*16 + cl)*64u + ((((unsigned)ks*4u + (unsigned)kgrp) ^ (unsigned)(cl & 7)) << 3);
      rB[z][ks] = (unsigned)(wc + z*16 + cl)*64u + ((((unsigned)ks*4u + (unsigned)kgrp) ^ (unsigned)(cl & 7)) << 3);
    }

  f32x4 acc[4][4] = {};

  for (int kt = 0; kt < (K >> 6); ++kt) {
    const int ko = kt << 6;
    #pragma unroll
    for (int q = 0; q < 4; ++q) {
      const unsigned i = (unsigned)(w*4 + q);
      gload_lds16(gA + ((size_t)i*8*K + ko), lA + i*512);
      gload_lds16(gB + ((size_t)i*8*K + ko), lB + i*512);
    }
    __syncthreads();
    #pragma unroll
    for (int ks = 0; ks < 2; ++ks) {
      bf16x8 af[4], bfr[4];
      #pragma unroll
      for (int i = 0; i < 4; ++i)
        af[i] = *reinterpret_cast<const bf16x8*>(&As[rA[i][ks]]);
      #pragma unroll
      for (int j = 0; j < 4; ++j)
        bfr[j] = *reinterpret_cast<const bf16x8*>(&Bs[rB[j][ks]]);
      #pragma unroll
      for (int i = 0; i < 4; ++i)
        #pragma unroll
        for (int j = 0; j < 4; ++j)
          acc[i][j] = MFMA16(af[i], bfr[j], acc[i][j]);
    }
    __syncthreads();
  }

  #pragma unroll
  for (int j = 0; j < 4; ++j) {
    const int col = n0 + wc + j*16 + cl;
    const float bj = bias[col];
    #pragma unroll
    for (int i = 0; i < 4; ++i) {
      const int row = m0 + wr + i*16 + rl;
      #pragma unroll
      for (int r = 0; r < 4; ++r)
        C[(size_t)(row + r) * E_ + col] = acc[i][j][r] + bj;
    }
  }
}

// ---------------- causal GQA flash attention (v19: single-strip blocks) -----------
// grid (16, 64): x = bh = b*8+h (-> XCD h via %8 dispatch), y: strip index
// sidx = 63 - y (LONGEST-FIRST dispatch for tail balance). Block = 4 waves =
// the 4 query heads sharing (b,h)'s K/V, handling ONE 32-row strip. 1024 blocks,
// 48KB LDS, launch_bounds(256,3) -> 3 blocks/CU resident (12 waves/CU) for
// cross-block latency hiding. Engine identical to v18 (verified): LDS-staged
// dbuf K/V, defer-max softmax, v_perm P-pack, ones-MFMA l, O^T=mfma(V^T,P).
__global__ __launch_bounds__(256, 3) void attn_kernel(
    const unsigned short* __restrict__ Q, const unsigned short* __restrict__ K,
    const unsigned short* __restrict__ Vt, unsigned short* __restrict__ O)
{
  __shared__ __align__(16) unsigned short Kbuf[2][4096];   // [64 kv][64 d] swizzled
  __shared__ __align__(16) unsigned short Vbuf[2][4096];   // [64 d][64 kv] swizzled
  __shared__ __align__(16) unsigned short Ps[4][2048];     // per-wave P
  const int tid  = threadIdx.x;
  const int w    = tid >> 6;
  const int lane = tid & 63;
  const int bh   = blockIdx.x;      // b*8 + h
  const int b    = bh >> 3;
  const int h    = bh & 7;
  const int sidx = 63 - (int)blockIdx.y;   // strip 63..0 (longest first)
  const int hq   = h*4 + w;         // this wave's query head
  const int cl   = lane & 15;
  const int kgrp = lane >> 4;
  const int rl   = kgrp << 2;
  const int li   = lane >> 3;       // 0..7 (staging row-in-group)
  const int lx   = lane & 7;        // 0..7 (staging chunk)

  const float K2  = 0.125f * 1.44269504088896340736f;  // SCALE * log2(e)
  const float THR = 16.0f;                              // defer-max bound (score units)

  char* pws = (char*)&Ps[w][0];
  const unsigned swz = ((unsigned)(cl & 7)) << 4;

  bf16x8 ones8;
  #pragma unroll
  for (int q = 0; q < 8; ++q) ones8[q] = (short)0x3F80;   // bf16 1.0

  const char* Kp = (const char*)(K + (size_t)(b*N_)*512 + h*64);
  const char* Vp = (const char*)(Vt + (size_t)(h*64)*BN_ + b*N_);

  // staging constants: instr i covers rows i*8+li; global chunk = (lx^li)
  const unsigned schunk = ((unsigned)(lx ^ li)) << 4;
  const unsigned kso  = (unsigned)li*1024u + schunk;   // + i*8192  + t*65536
  const unsigned vso  = (unsigned)li*8192u + schunk;   // + i*65536 + t*128
  const unsigned ldst = (unsigned)lane*16u;            // + i*1024

  // fragment read offsets: row z*16+cl, chunk (ks*4+kgrp)^(cl&7)
  unsigned rdo[4][2];
  #pragma unroll
  for (int z = 0; z < 4; ++z)
    #pragma unroll
    for (int ks = 0; ks < 2; ++ks)
      rdo[z][ks] = (unsigned)z*2048u + (unsigned)cl*128u
                 + ((((unsigned)ks*4u + (unsigned)kgrp) ^ (unsigned)(cl & 7)) << 4);

  // P LDS offsets: write b64 (4 kv), read b128 (8 kv)
  unsigned wb[2][4], rb[2][2];
  #pragma unroll
  for (int i = 0; i < 2; ++i) {
    #pragma unroll
    for (int c = 0; c < 4; ++c)
      wb[i][c] = (unsigned)i*2048u + (unsigned)cl*128u
               + (((unsigned)c*32u + (unsigned)kgrp*8u) ^ swz);
    #pragma unroll
    for (int ks = 0; ks < 2; ++ks)
      rb[i][ks] = (unsigned)i*2048u + (unsigned)cl*128u
                + (((unsigned)ks*64u + (unsigned)kgrp*16u) ^ swz);
  }

  const int q0 = sidx << 5;
  const int nt = (sidx >> 1) + 1;   // kv tiles of 64

  // Q fragments (B-operand): lane cl = q row
  bf16x8 qf[2][2];
  #pragma unroll
  for (int i = 0; i < 2; ++i) {
    const size_t qoff = (size_t)(b*N_ + q0 + i*16 + cl) * E_ + hq*64 + (kgrp << 3);
    qf[i][0] = *reinterpret_cast<const bf16x8*>(Q + qoff);
    qf[i][1] = *reinterpret_cast<const bf16x8*>(Q + qoff + 32);
  }

  f32x4 o[2][4] = {};
  f32x4 l4[2] = {};
  float m[2] = {-1e30f, -1e30f};

  // stage tile 0 into buffer 0 (each wave: 2 K + 2 V instructions)
  #pragma unroll
  for (int q = 0; q < 2; ++q) {
    const unsigned i = (unsigned)(w*2 + q);
    gload_lds16(Kp + (i*8192u + kso),  (char*)Kbuf[0] + (i*1024u + ldst));
    gload_lds16(Vp + (i*65536u + vso), (char*)Vbuf[0] + (i*1024u + ldst));
  }
  int cur = 0;
  __syncthreads();   // drain stage

  for (int t = 0; t < nt; ++t) {
    // ---- stage tile t+1 into other buffer (overlaps with compute below) ----
    if (t + 1 < nt) {
      const unsigned kt = (unsigned)(t + 1) * 65536u;
      const unsigned vt = (unsigned)(t + 1) * 128u;
      #pragma unroll
      for (int q = 0; q < 2; ++q) {
        const unsigned i = (unsigned)(w*2 + q);
        gload_lds16(Kp + (kt + i*8192u + kso),  (char*)Kbuf[cur^1] + (i*1024u + ldst));
        gload_lds16(Vp + (vt + i*65536u + vso), (char*)Vbuf[cur^1] + (i*1024u + ldst));
      }
    }

    // ---- K fragments from LDS ----
    bf16x8 kf[4][2];
    #pragma unroll
    for (int c = 0; c < 4; ++c)
      #pragma unroll
      for (int ks = 0; ks < 2; ++ks)
        kf[c][ks] = *reinterpret_cast<const bf16x8*>((const char*)Kbuf[cur] + rdo[c][ks]);

    // ---- S^T = K Q ----
    f32x4 s[2][4];
    #pragma unroll
    for (int i = 0; i < 2; ++i)
      #pragma unroll
      for (int c = 0; c < 4; ++c) {
        f32x4 z = {};
        z = MFMA16(kf[c][0], qf[i][0], z);
        z = MFMA16(kf[c][1], qf[i][1], z);
        s[i][c] = z;
      }

    // ---- causal mask (last tile only): kv > q -> -inf ----
    if (t == nt - 1) {
      const int kvb = t << 6;
      #pragma unroll
      for (int i = 0; i < 2; ++i) {
        const int qq = q0 + i*16 + cl;
        #pragma unroll
        for (int c = 0; c < 4; ++c)
          #pragma unroll
          for (int r = 0; r < 4; ++r)
            if (kvb + c*16 + rl + r > qq) s[i][c][r] = -1e30f;
      }
    }

    // ---- softmax per i-block: DEFER-MAX (T13) + v_perm P-pack ----
    #pragma unroll
    for (int i = 0; i < 2; ++i) {
      float t0 = fmaxf(fmaxf(s[i][0][0], s[i][0][1]), fmaxf(s[i][0][2], s[i][0][3]));
      float t1 = fmaxf(fmaxf(s[i][1][0], s[i][1][1]), fmaxf(s[i][1][2], s[i][1][3]));
      float t2 = fmaxf(fmaxf(s[i][2][0], s[i][2][1]), fmaxf(s[i][2][2], s[i][2][3]));
      float t3 = fmaxf(fmaxf(s[i][3][0], s[i][3][1]), fmaxf(s[i][3][2], s[i][3][3]));
      const float lm = fmaxf(fmaxf(t0, t1), fmaxf(t2, t3));  // lane-local partial max
      if (!__all(lm <= m[i] + THR)) {
        // rare path (first tile + occasional growth): exact reduce + rescale
        float tm = lm;
        tm = fmaxf(tm, __shfl_xor(tm, 16, 64));
        tm = fmaxf(tm, __shfl_xor(tm, 32, 64));
        const float mn = fmaxf(m[i], tm);
        const float al = __builtin_amdgcn_exp2f(K2 * (m[i] - mn));
        m[i] = mn;
        l4[i] *= al;
        #pragma unroll
        for (int db = 0; db < 4; ++db) o[i][db] *= al;
      }
      const float mn = m[i];
      #pragma unroll
      for (int c = 0; c < 4; ++c) {
        const float e0 = __builtin_amdgcn_exp2f(K2 * (s[i][c][0] - mn));
        const float e1 = __builtin_amdgcn_exp2f(K2 * (s[i][c][1] - mn));
        const float e2 = __builtin_amdgcn_exp2f(K2 * (s[i][c][2] - mn));
        const float e3 = __builtin_amdgcn_exp2f(K2 * (s[i][c][3] - mn));
        uint2 u;
        u.x = pack_bf16_trunc(e0, e1);
        u.y = pack_bf16_trunc(e2, e3);
        *reinterpret_cast<uint2*>(pws + wb[i][c]) = u;
      }
    }

    // ---- V fragments from LDS ----
    bf16x8 vf[4][2];
    #pragma unroll
    for (int db = 0; db < 4; ++db)
      #pragma unroll
      for (int ks = 0; ks < 2; ++ks)
        vf[db][ks] = *reinterpret_cast<const bf16x8*>((const char*)Vbuf[cur] + rdo[db][ks]);

    // ---- O^T += V^T P ; l += 1 . P ----
    #pragma unroll
    for (int i = 0; i < 2; ++i) {
      const bf16x8 pa0 = *reinterpret_cast<const bf16x8*>(pws + rb[i][0]);
      const bf16x8 pa1 = *reinterpret_cast<const bf16x8*>(pws + rb[i][1]);
      l4[i] = MFMA16(ones8, pa0, l4[i]);
      l4[i] = MFMA16(ones8, pa1, l4[i]);
      #pragma unroll
      for (int db = 0; db < 4; ++db) {
        o[i][db] = MFMA16(vf[db][0], pa0, o[i][db]);
        o[i][db] = MFMA16(vf[db][1], pa1, o[i][db]);
      }
    }

    __syncthreads();   // stage(t+1) drained + all waves done reading buf[cur]
    cur ^= 1;
  }

  // ---- epilogue: O[q][hq*64 + d] = o/l (RNE f2bf, 8B stores) ----
  #pragma unroll
  for (int i = 0; i < 2; ++i) {
    const float inv = 1.0f / l4[i][0];
    const size_t orow = (size_t)(b*N_ + q0 + i*16 + cl) * E_ + hq*64 + rl;
    #pragma unroll
    for (int db = 0; db < 4; ++db) {
      ushort4 u;
      u.x = f2bf(o[i][db][0] * inv);
      u.y = f2bf(o[i][db][1] * inv);
      u.z = f2bf(o[i][db][2] * inv);
      u.w = f2bf(o[i][db][3] * inv);
      *reinterpret_cast<ushort4*>(&O[orow + db*16]) = u;
    }
  }
}

extern "C" void kernel_launch(void* const* d_in, const int* in_sizes, int n_in,
                              void* d_out, int out_size, void* d_ws, size_t ws_size,
                              hipStream_t stream) {
  const float* x  = (const float*)d_in[0];
  const float* Wq = (const float*)d_in[1];
  const float* bq = (const float*)d_in[2];
  const float* Wk = (const float*)d_in[3];
  const float* bk = (const float*)d_in[4];
  const float* Wv = (const float*)d_in[5];
  const float* bv = (const float*)d_in[6];
  const float* Wo = (const float*)d_in[7];
  const float* bo = (const float*)d_in[8];
  float* out = (float*)d_out;

  // workspace carve (bf16 elements); cast destinations contiguous in input order
  unsigned short* ws  = (unsigned short*)d_ws;
  unsigned short* xb  = ws;              // 4096x2048
  unsigned short* Wqb = xb  + 8388608;   // 2048x2048
  unsigned short* Wkb = Wqb + 4194304;   // 512x2048
  unsigned short* Wvb = Wkb + 1048576;   // 512x2048
  unsigned short* Wob = Wvb + 1048576;   // 2048x2048
  unsigned short* Qb  = Wob + 4194304;   // 4096x2048
  unsigned short* Kb  = Qb  + 8388608;   // 4096x512
  unsigned short* Vtb = Kb  + 2097152;   // 512x4096 (V transposed)
  unsigned short* Ob  = Vtb + 2097152;   // 4096x2048

  cast_all<<<dim3(2048), dim3(256), 0, stream>>>(x, Wq, Wk, Wv, Wo, xb);

  gemm_qkv<<<dim3(512), dim3(512), 0, stream>>>(xb, Wqb, Wkb, Wvb,
                                                bq, bk, bv, Qb, Kb, Vtb);

  attn_kernel<<<dim3(16, 64), dim3(256), 0, stream>>>(Qb, Kb, Vtb, Ob);

  gemm_out<<<dim3(32*16), dim3(256), 0, stream>>>(Ob, Wob, bo, out);
}

// Round 20
// 162.832 us; speedup vs baseline: 1.2559x; 1.0273x over previous
//
#include <hip/hip_runtime.h>
#include <hip/hip_bf16.h>

// FlashMultiHeadAttention: x -> QKV proj -> causal GQA flash attn -> out proj
// B=2 N=2048 E=2048 HQ=32 HKV=8 D=64 G=4. All compute in bf16 MFMA, fp32 accum.
// Q is pre-scaled by K2 = SCALE*log2(e) at projection time, so attention
// scores are already in log2 units (exp2(s - m) directly).

#define B_   2
#define N_   2048
#define E_   2048
#define HQ_  32
#define HKV_ 8
#define D_   64
#define BN_  (B_*N_)   // 4096 total rows

typedef __attribute__((ext_vector_type(8))) short bf16x8;
typedef __attribute__((ext_vector_type(4))) float f32x4;

#define MFMA16(a,b,c) __builtin_amdgcn_mfma_f32_16x16x32_bf16(a,b,c,0,0,0)

__device__ inline unsigned short f2bf(float f) {
  unsigned u = __builtin_bit_cast(unsigned, f);
  u += 0x7FFFu + ((u >> 16) & 1u);   // RNE
  return (unsigned short)(u >> 16);
}

// pack two f32 -> two truncated bf16 in one v_perm_b32 (P >= 0 so trunc = floor;
// <= 1 ulp (2^-8 rel) vs RNE, bias cancels in O/l). NOTE: v_cvt_pk_bf16_f32
// inline asm produced corrupt results on this toolchain (rounds 6 & 17) - do
// not reintroduce it.
__device__ inline unsigned pack_bf16_trunc(float lo, float hi) {
  return __builtin_amdgcn_perm(__builtin_bit_cast(unsigned, hi),
                               __builtin_bit_cast(unsigned, lo), 0x07060302u);
}

__device__ inline void gload_lds16(const void* g, void* l) {
  __builtin_amdgcn_global_load_lds(
      (const __attribute__((address_space(1))) void*)g,
      (__attribute__((address_space(3))) void*)l, 16, 0, 0);
}

// ---------------- fused cast fp32 -> bf16 for x,Wq,Wk,Wv,Wo ----------------
__global__ void cast_all(const float* __restrict__ x,  const float* __restrict__ wq,
                         const float* __restrict__ wk, const float* __restrict__ wv,
                         const float* __restrict__ wo, unsigned short* __restrict__ dst) {
  const int c0 = 2097152;            // x      (8388608 elems /4)
  const int c1 = c0 + 1048576;       // Wq
  const int c2 = c1 + 262144;        // Wk
  const int c3 = c2 + 262144;        // Wv
  const int c4 = c3 + 1048576;       // Wo
  int i = blockIdx.x * blockDim.x + threadIdx.x;
  const int stride = gridDim.x * blockDim.x;
  for (; i < c4; i += stride) {
    const float* src; int off;
    if      (i < c0) { src = x;  off = i; }
    else if (i < c1) { src = wq; off = i - c0; }
    else if (i < c2) { src = wk; off = i - c1; }
    else if (i < c3) { src = wv; off = i - c2; }
    else             { src = wo; off = i - c3; }
    float4 f = reinterpret_cast<const float4*>(src)[off];
    ushort4 u;
    u.x = f2bf(f.x); u.y = f2bf(f.y); u.z = f2bf(f.z); u.w = f2bf(f.w);
    reinterpret_cast<ushort4*>(dst)[i] = u;
  }
}

// ---------------- fused QKV projection GEMM: 128x192 tile, EXACT 2-blocks/CU ------
// (v15-verified) BM=128, BN=192 (virtual QKV cols 3072 = 16 x 192), BK=64.
// Grid 512 = exactly 2 per CU. 8 waves (2M x 4N), per-wave 64x48 (acc[4][3]).
// LDS dbuf: As[2][128x64] + Bs[2][192x64] = 80KB. Thin counted-vmcnt schedule.
// Q output (seg 0) is scaled by K2 = SCALE*log2(e) for log2-unit attn scores.
__global__ __launch_bounds__(512, 4) void gemm_qkv(
    const unsigned short* __restrict__ A,
    const unsigned short* __restrict__ Wq, const unsigned short* __restrict__ Wk,
    const unsigned short* __restrict__ Wv,
    const float* __restrict__ bq, const float* __restrict__ bk, const float* __restrict__ bv,
    unsigned short* __restrict__ Qo, unsigned short* __restrict__ Ko,
    unsigned short* __restrict__ Vto)
{
  __shared__ __align__(16) unsigned short As[2][8192];    // [buf][128*64]  2x16KB
  __shared__ __align__(16) unsigned short Bs[2][12288];   // [buf][192*64]  2x24KB
  const int tid  = threadIdx.x;
  const int w    = tid >> 6;
  const int lane = tid & 63;
  const int g    = blockIdx.x & 7;        // XCD slot
  const int s    = blockIdx.x >> 3;       // 0..63
  const int bm   = g*4 + (s >> 4);        // 0..31 (4 bm-panels per XCD)
  const int bn   = s & 15;                // 0..15
  const int m0   = bm << 7;
  const int n0v  = bn * 192;              // virtual col in [Q|K|V] = 3072
  const int K    = E_;
  const float K2S = 0.125f * 1.44269504088896340736f;   // SCALE * log2(e)

  const int mgrp = w >> 2;                // 0/1: rows mgrp*64
  const int ngrp = w & 3;                 // cols ngrp*48
  const int cl   = lane & 15;
  const int kgrp = lane >> 4;
  const int rl   = kgrp << 2;
  const int li   = lane >> 3;             // staging row-in-group 0..7
  const int lx   = lane & 7;              // staging chunk 0..7

  // staging bases; global chunk = lx^li (inverse swizzle)
  const unsigned gsw = ((unsigned)(lx ^ li)) << 3;   // elems
  const unsigned short* gA = A + (size_t)(m0 + w*16 + li) * K + gsw;
  const unsigned short* gBq[3];
  #pragma unroll
  for (int q = 0; q < 3; ++q) {
    const int vr = n0v + w*24 + q*8;      // seg-uniform (2048/2560 % 8 == 0)
    const unsigned short* base;
    if (vr < 2048)      base = Wq + (size_t)vr * K;
    else if (vr < 2560) base = Wk + (size_t)(vr - 2048) * K;
    else                base = Wv + (size_t)(vr - 2560) * K;
    gBq[q] = base + (size_t)li * K + gsw;
  }
  const unsigned aDst = (unsigned)(w*16)*64u + (unsigned)lane*8u;  // elems
  const unsigned bDst = (unsigned)(w*24)*64u + (unsigned)lane*8u;

  // read offsets (elems): row*64 + ((ks*4+kgrp)^(cl&7))*8
  unsigned rAo[4][2], rBo[3][2];
  #pragma unroll
  for (int ks = 0; ks < 2; ++ks) {
    const unsigned c8 = (((unsigned)(ks*4 + kgrp)) ^ (unsigned)(cl & 7)) << 3;
    #pragma unroll
    for (int z = 0; z < 4; ++z)
      rAo[z][ks] = (unsigned)(mgrp*64 + z*16 + cl) * 64u + c8;
    #pragma unroll
    for (int jj = 0; jj < 3; ++jj)
      rBo[jj][ks] = (unsigned)(ngrp*48 + jj*16 + cl) * 64u + c8;
  }

  f32x4 acc[4][3] = {};
  const int nt = K >> 6;   // 32

  auto STAGE = [&](int kt, int buf) {   // 5 wave-loads: 2 A + 3 B
    const int ko = kt << 6;
    #pragma unroll
    for (int q = 0; q < 2; ++q)
      gload_lds16(gA + (size_t)(q*8)*K + ko, &As[buf][aDst + q*512u]);
    #pragma unroll
    for (int q = 0; q < 3; ++q)
      gload_lds16(gBq[q] + ko, &Bs[buf][bDst + q*512u]);
  };

  STAGE(0, 0);
  int p = 0;

  for (int t = 0; t < nt; ++t) {
    if (t + 1 < nt) {
      STAGE(t + 1, p ^ 1);
      asm volatile("s_waitcnt vmcnt(5)" ::: "memory");   // tile-t landed
    } else {
      asm volatile("s_waitcnt vmcnt(0)" ::: "memory");
    }
    __builtin_amdgcn_s_barrier();
    #pragma unroll
    for (int ks = 0; ks < 2; ++ks) {
      bf16x8 af[4], bfr[3];
      #pragma unroll
      for (int z = 0; z < 4; ++z)
        af[z] = *reinterpret_cast<const bf16x8*>(&As[p][rAo[z][ks]]);
      #pragma unroll
      for (int jj = 0; jj < 3; ++jj)
        bfr[jj] = *reinterpret_cast<const bf16x8*>(&Bs[p][rBo[jj][ks]]);
      __builtin_amdgcn_s_setprio(1);
      #pragma unroll
      for (int z = 0; z < 4; ++z)
        #pragma unroll
        for (int jj = 0; jj < 3; ++jj)
          acc[z][jj] = MFMA16(af[z], bfr[jj], acc[z][jj]);
      __builtin_amdgcn_s_setprio(0);
    }
    __builtin_amdgcn_s_barrier();   // reads consumed -> safe to restage buf p
    p ^= 1;
  }

  // epilogue: per-(jj) 16-col fragment is segment-uniform (2048/2560 % 16 == 0)
  #pragma unroll
  for (int z = 0; z < 4; ++z) {
    const int rowb = m0 + mgrp*64 + z*16 + rl;
    #pragma unroll
    for (int jj = 0; jj < 3; ++jj) {
      const int col16 = n0v + ngrp*48 + jj*16;
      if (col16 < 2048) {
        const int col = col16 + cl;
        const float bj = bq[col];
        #pragma unroll
        for (int r = 0; r < 4; ++r)
          Qo[(size_t)(rowb + r) * 2048 + col] = f2bf((acc[z][jj][r] + bj) * K2S);
      } else if (col16 < 2560) {
        const int col = col16 - 2048 + cl;
        const float bj = bk[col];
        #pragma unroll
        for (int r = 0; r < 4; ++r)
          Ko[(size_t)(rowb + r) * 512 + col] = f2bf(acc[z][jj][r] + bj);
      } else {
        const int col = col16 - 2560 + cl;
        const float bj = bv[col];
        ushort4 u;
        u.x = f2bf(acc[z][jj][0] + bj);
        u.y = f2bf(acc[z][jj][1] + bj);
        u.z = f2bf(acc[z][jj][2] + bj);
        u.w = f2bf(acc[z][jj][3] + bj);
        *reinterpret_cast<ushort4*>(&Vto[(size_t)col * 4096 + rowb]) = u;
      }
    }
  }
}

// ---------------- out-proj GEMM (v9 engine: BK=64 single-buffer, fp32 out) --------
__global__ __launch_bounds__(256) void gemm_out(
    const unsigned short* __restrict__ A, const unsigned short* __restrict__ W,
    const float* __restrict__ bias, float* __restrict__ C)
{
  __shared__ __align__(16) unsigned short As[128*64];
  __shared__ __align__(16) unsigned short Bs[128*64];
  const int tid  = threadIdx.x;
  const int w    = tid >> 6;
  const int lane = tid & 63;
  const int bm   = blockIdx.x >> 4;
  const int bn   = blockIdx.x & 15;
  const int m0   = bm << 7, n0 = bn << 7;
  const int K    = E_;
  const int wr   = (w >> 1) << 6;
  const int wc   = (w & 1) << 6;
  const int cl   = lane & 15;
  const int kgrp = lane >> 4;
  const int rl   = kgrp << 2;
  const int li   = lane >> 3;
  const int lx   = lane & 7;

  const unsigned schunk = ((unsigned)(lx ^ li)) << 3;
  const unsigned short* gA = A + (size_t)(m0 + li) * K + schunk;
  const unsigned short* gB = W + (size_t)(n0 + li) * K + schunk;
  unsigned short* lA = As + lane*8;
  unsigned short* lB = Bs + lane*8;

  unsigned rA[4][2], rB[4][2];
  #pragma unroll
  for (int z = 0; z < 4; ++z)
    #pragma unroll
    for (int ks = 0; ks < 2; ++ks) {
      rA[z][ks] = (unsigned)(wr + z*16 + cl)*64u + ((((unsigned)ks*4u + (unsigned)kgrp) ^ (unsigned)(cl & 7)) << 3);
      rB[z][ks] = (unsigned)(wc + z*16 + cl)*64u + ((((unsigned)ks*4u + (unsigned)kgrp) ^ (unsigned)(cl & 7)) << 3);
    }

  f32x4 acc[4][4] = {};

  for (int kt = 0; kt < (K >> 6); ++kt) {
    const int ko = kt << 6;
    #pragma unroll
    for (int q = 0; q < 4; ++q) {
      const unsigned i = (unsigned)(w*4 + q);
      gload_lds16(gA + ((size_t)i*8*K + ko), lA + i*512);
      gload_lds16(gB + ((size_t)i*8*K + ko), lB + i*512);
    }
    __syncthreads();
    #pragma unroll
    for (int ks = 0; ks < 2; ++ks) {
      bf16x8 af[4], bfr[4];
      #pragma unroll
      for (int i = 0; i < 4; ++i)
        af[i] = *reinterpret_cast<const bf16x8*>(&As[rA[i][ks]]);
      #pragma unroll
      for (int j = 0; j < 4; ++j)
        bfr[j] = *reinterpret_cast<const bf16x8*>(&Bs[rB[j][ks]]);
      #pragma unroll
      for (int i = 0; i < 4; ++i)
        #pragma unroll
        for (int j = 0; j < 4; ++j)
          acc[i][j] = MFMA16(af[i], bfr[j], acc[i][j]);
    }
    __syncthreads();
  }

  #pragma unroll
  for (int j = 0; j < 4; ++j) {
    const int col = n0 + wc + j*16 + cl;
    const float bj = bias[col];
    #pragma unroll
    for (int i = 0; i < 4; ++i) {
      const int row = m0 + wr + i*16 + rl;
      #pragma unroll
      for (int r = 0; r < 4; ++r)
        C[(size_t)(row + r) * E_ + col] = acc[i][j][r] + bj;
    }
  }
}

// ---------------- causal GQA flash attention (v20: log2-unit scores) --------------
// grid (16, 64): x = bh = b*8+h (-> XCD h via %8 dispatch), y: strip index
// sidx = 63 - y (longest-first). Block = 4 waves = the 4 query heads sharing
// (b,h)'s K/V, one 32-row strip, 3 blocks/CU. Engine = v19 (verified) except:
// Q pre-scaled by K2 at projection, so exp2(s - m) directly (saves 32 VALU
// mul/tile); THR = 3.0 (log2 units, P <= 8); max tree in max3-fusable form.
__global__ __launch_bounds__(256, 3) void attn_kernel(
    const unsigned short* __restrict__ Q, const unsigned short* __restrict__ K,
    const unsigned short* __restrict__ Vt, unsigned short* __restrict__ O)
{
  __shared__ __align__(16) unsigned short Kbuf[2][4096];   // [64 kv][64 d] swizzled
  __shared__ __align__(16) unsigned short Vbuf[2][4096];   // [64 d][64 kv] swizzled
  __shared__ __align__(16) unsigned short Ps[4][2048];     // per-wave P
  const int tid  = threadIdx.x;
  const int w    = tid >> 6;
  const int lane = tid & 63;
  const int bh   = blockIdx.x;      // b*8 + h
  const int b    = bh >> 3;
  const int h    = bh & 7;
  const int sidx = 63 - (int)blockIdx.y;   // strip 63..0 (longest first)
  const int hq   = h*4 + w;         // this wave's query head
  const int cl   = lane & 15;
  const int kgrp = lane >> 4;
  const int rl   = kgrp << 2;
  const int li   = lane >> 3;       // 0..7 (staging row-in-group)
  const int lx   = lane & 7;        // 0..7 (staging chunk)

  const float THR = 3.0f;           // defer-max bound (log2 units): P <= 2^3 = 8

  char* pws = (char*)&Ps[w][0];
  const unsigned swz = ((unsigned)(cl & 7)) << 4;

  bf16x8 ones8;
  #pragma unroll
  for (int q = 0; q < 8; ++q) ones8[q] = (short)0x3F80;   // bf16 1.0

  const char* Kp = (const char*)(K + (size_t)(b*N_)*512 + h*64);
  const char* Vp = (const char*)(Vt + (size_t)(h*64)*BN_ + b*N_);

  // staging constants: instr i covers rows i*8+li; global chunk = (lx^li)
  const unsigned schunk = ((unsigned)(lx ^ li)) << 4;
  const unsigned kso  = (unsigned)li*1024u + schunk;   // + i*8192  + t*65536
  const unsigned vso  = (unsigned)li*8192u + schunk;   // + i*65536 + t*128
  const unsigned ldst = (unsigned)lane*16u;            // + i*1024

  // fragment read offsets: row z*16+cl, chunk (ks*4+kgrp)^(cl&7)
  unsigned rdo[4][2];
  #pragma unroll
  for (int z = 0; z < 4; ++z)
    #pragma unroll
    for (int ks = 0; ks < 2; ++ks)
      rdo[z][ks] = (unsigned)z*2048u + (unsigned)cl*128u
                 + ((((unsigned)ks*4u + (unsigned)kgrp) ^ (unsigned)(cl & 7)) << 4);

  // P LDS offsets: write b64 (4 kv), read b128 (8 kv)
  unsigned wb[2][4], rb[2][2];
  #pragma unroll
  for (int i = 0; i < 2; ++i) {
    #pragma unroll
    for (int c = 0; c < 4; ++c)
      wb[i][c] = (unsigned)i*2048u + (unsigned)cl*128u
               + (((unsigned)c*32u + (unsigned)kgrp*8u) ^ swz);
    #pragma unroll
    for (int ks = 0; ks < 2; ++ks)
      rb[i][ks] = (unsigned)i*2048u + (unsigned)cl*128u
                + (((unsigned)ks*64u + (unsigned)kgrp*16u) ^ swz);
  }

  const int q0 = sidx << 5;
  const int nt = (sidx >> 1) + 1;   // kv tiles of 64

  // Q fragments (B-operand): lane cl = q row
  bf16x8 qf[2][2];
  #pragma unroll
  for (int i = 0; i < 2; ++i) {
    const size_t qoff = (size_t)(b*N_ + q0 + i*16 + cl) * E_ + hq*64 + (kgrp << 3);
    qf[i][0] = *reinterpret_cast<const bf16x8*>(Q + qoff);
    qf[i][1] = *reinterpret_cast<const bf16x8*>(Q + qoff + 32);
  }

  f32x4 o[2][4] = {};
  f32x4 l4[2] = {};
  float m[2] = {-1e30f, -1e30f};

  // stage tile 0 into buffer 0 (each wave: 2 K + 2 V instructions)
  #pragma unroll
  for (int q = 0; q < 2; ++q) {
    const unsigned i = (unsigned)(w*2 + q);
    gload_lds16(Kp + (i*8192u + kso),  (char*)Kbuf[0] + (i*1024u + ldst));
    gload_lds16(Vp + (i*65536u + vso), (char*)Vbuf[0] + (i*1024u + ldst));
  }
  int cur = 0;
  __syncthreads();   // drain stage

  for (int t = 0; t < nt; ++t) {
    // ---- stage tile t+1 into other buffer (overlaps with compute below) ----
    if (t + 1 < nt) {
      const unsigned kt = (unsigned)(t + 1) * 65536u;
      const unsigned vt = (unsigned)(t + 1) * 128u;
      #pragma unroll
      for (int q = 0; q < 2; ++q) {
        const unsigned i = (unsigned)(w*2 + q);
        gload_lds16(Kp + (kt + i*8192u + kso),  (char*)Kbuf[cur^1] + (i*1024u + ldst));
        gload_lds16(Vp + (vt + i*65536u + vso), (char*)Vbuf[cur^1] + (i*1024u + ldst));
      }
    }

    // ---- K fragments from LDS ----
    bf16x8 kf[4][2];
    #pragma unroll
    for (int c = 0; c < 4; ++c)
      #pragma unroll
      for (int ks = 0; ks < 2; ++ks)
        kf[c][ks] = *reinterpret_cast<const bf16x8*>((const char*)Kbuf[cur] + rdo[c][ks]);

    // ---- S^T = K Q (log2 units; Q pre-scaled by K2) ----
    f32x4 s[2][4];
    #pragma unroll
    for (int i = 0; i < 2; ++i)
      #pragma unroll
      for (int c = 0; c < 4; ++c) {
        f32x4 z = {};
        z = MFMA16(kf[c][0], qf[i][0], z);
        z = MFMA16(kf[c][1], qf[i][1], z);
        s[i][c] = z;
      }

    // ---- causal mask (last tile only): kv > q -> -inf ----
    if (t == nt - 1) {
      const int kvb = t << 6;
      #pragma unroll
      for (int i = 0; i < 2; ++i) {
        const int qq = q0 + i*16 + cl;
        #pragma unroll
        for (int c = 0; c < 4; ++c)
          #pragma unroll
          for (int r = 0; r < 4; ++r)
            if (kvb + c*16 + rl + r > qq) s[i][c][r] = -1e30f;
      }
    }

    // ---- softmax per i-block: DEFER-MAX (T13), max3 tree, v_perm P-pack ----
    #pragma unroll
    for (int i = 0; i < 2; ++i) {
      const float v0 = fmaxf(fmaxf(s[i][0][0], s[i][0][1]), s[i][0][2]);
      const float v1 = fmaxf(fmaxf(s[i][0][3], s[i][1][0]), s[i][1][1]);
      const float v2 = fmaxf(fmaxf(s[i][1][2], s[i][1][3]), s[i][2][0]);
      const float v3 = fmaxf(fmaxf(s[i][2][1], s[i][2][2]), s[i][2][3]);
      const float v4 = fmaxf(fmaxf(s[i][3][0], s[i][3][1]), s[i][3][2]);
      const float lm = fmaxf(fmaxf(fmaxf(v0, v1), v2),
                             fmaxf(fmaxf(v3, v4), s[i][3][3]));
      if (!__all(lm <= m[i] + THR)) {
        // rare path (first tile + occasional growth): exact reduce + rescale
        float tm = lm;
        tm = fmaxf(tm, __shfl_xor(tm, 16, 64));
        tm = fmaxf(tm, __shfl_xor(tm, 32, 64));
        const float mn = fmaxf(m[i], tm);
        const float al = __builtin_amdgcn_exp2f(m[i] - mn);
        m[i] = mn;
        l4[i] *= al;
        #pragma unroll
        for (int db = 0; db < 4; ++db) o[i][db] *= al;
      }
      const float mn = m[i];
      #pragma unroll
      for (int c = 0; c < 4; ++c) {
        const float e0 = __builtin_amdgcn_exp2f(s[i][c][0] - mn);
        const float e1 = __builtin_amdgcn_exp2f(s[i][c][1] - mn);
        const float e2 = __builtin_amdgcn_exp2f(s[i][c][2] - mn);
        const float e3 = __builtin_amdgcn_exp2f(s[i][c][3] - mn);
        uint2 u;
        u.x = pack_bf16_trunc(e0, e1);
        u.y = pack_bf16_trunc(e2, e3);
        *reinterpret_cast<uint2*>(pws + wb[i][c]) = u;
      }
    }

    // ---- V fragments from LDS ----
    bf16x8 vf[4][2];
    #pragma unroll
    for (int db = 0; db < 4; ++db)
      #pragma unroll
      for (int ks = 0; ks < 2; ++ks)
        vf[db][ks] = *reinterpret_cast<const bf16x8*>((const char*)Vbuf[cur] + rdo[db][ks]);

    // ---- O^T += V^T P ; l += 1 . P ----
    #pragma unroll
    for (int i = 0; i < 2; ++i) {
      const bf16x8 pa0 = *reinterpret_cast<const bf16x8*>(pws + rb[i][0]);
      const bf16x8 pa1 = *reinterpret_cast<const bf16x8*>(pws + rb[i][1]);
      l4[i] = MFMA16(ones8, pa0, l4[i]);
      l4[i] = MFMA16(ones8, pa1, l4[i]);
      #pragma unroll
      for (int db = 0; db < 4; ++db) {
        o[i][db] = MFMA16(vf[db][0], pa0, o[i][db]);
        o[i][db] = MFMA16(vf[db][1], pa1, o[i][db]);
      }
    }

    __syncthreads();   // stage(t+1) drained + all waves done reading buf[cur]
    cur ^= 1;
  }

  // ---- epilogue: O[q][hq*64 + d] = o/l (RNE f2bf, 8B stores) ----
  #pragma unroll
  for (int i = 0; i < 2; ++i) {
    const float inv = 1.0f / l4[i][0];
    const size_t orow = (size_t)(b*N_ + q0 + i*16 + cl) * E_ + hq*64 + rl;
    #pragma unroll
    for (int db = 0; db < 4; ++db) {
      ushort4 u;
      u.x = f2bf(o[i][db][0] * inv);
      u.y = f2bf(o[i][db][1] * inv);
      u.z = f2bf(o[i][db][2] * inv);
      u.w = f2bf(o[i][db][3] * inv);
      *reinterpret_cast<ushort4*>(&O[orow + db*16]) = u;
    }
  }
}

extern "C" void kernel_launch(void* const* d_in, const int* in_sizes, int n_in,
                              void* d_out, int out_size, void* d_ws, size_t ws_size,
                              hipStream_t stream) {
  const float* x  = (const float*)d_in[0];
  const float* Wq = (const float*)d_in[1];
  const float* bq = (const float*)d_in[2];
  const float* Wk = (const float*)d_in[3];
  const float* bk = (const float*)d_in[4];
  const float* Wv = (const float*)d_in[5];
  const float* bv = (const float*)d_in[6];
  const float* Wo = (const float*)d_in[7];
  const float* bo = (const float*)d_in[8];
  float* out = (float*)d_out;

  // workspace carve (bf16 elements); cast destinations contiguous in input order
  unsigned short* ws  = (unsigned short*)d_ws;
  unsigned short* xb  = ws;              // 4096x2048
  unsigned short* Wqb = xb  + 8388608;   // 2048x2048
  unsigned short* Wkb = Wqb + 4194304;   // 512x2048
  unsigned short* Wvb = Wkb + 1048576;   // 512x2048
  unsigned short* Wob = Wvb + 1048576;   // 2048x2048
  unsigned short* Qb  = Wob + 4194304;   // 4096x2048
  unsigned short* Kb  = Qb  + 8388608;   // 4096x512
  unsigned short* Vtb = Kb  + 2097152;   // 512x4096 (V transposed)
  unsigned short* Ob  = Vtb + 2097152;   // 4096x2048

  cast_all<<<dim3(2048), dim3(256), 0, stream>>>(x, Wq, Wk, Wv, Wo, xb);

  gemm_qkv<<<dim3(512), dim3(512), 0, stream>>>(xb, Wqb, Wkb, Wvb,
                                                bq, bk, bv, Qb, Kb, Vtb);

  attn_kernel<<<dim3(16, 64), dim3(256), 0, stream>>>(Qb, Kb, Vtb, Ob);

  gemm_out<<<dim3(32*16), dim3(256), 0, stream>>>(Ob, Wob, bo, out);
}

// Round 21
// 158.045 us; speedup vs baseline: 1.2940x; 1.0303x over previous
//
#include <hip/hip_runtime.h>
#include <hip/hip_bf16.h>

// FlashMultiHeadAttention: x -> QKV proj -> causal GQA flash attn -> out proj
// B=2 N=2048 E=2048 HQ=32 HKV=8 D=64 G=4. All compute in bf16 MFMA, fp32 accum.
// Q is pre-scaled by K2 = SCALE*log2(e) at projection time, so attention
// scores are already in log2 units (exp2(s - m) directly).

#define B_   2
#define N_   2048
#define E_   2048
#define HQ_  32
#define HKV_ 8
#define D_   64
#define BN_  (B_*N_)   // 4096 total rows

typedef __attribute__((ext_vector_type(8))) short bf16x8;
typedef __attribute__((ext_vector_type(4))) float f32x4;

#define MFMA16(a,b,c) __builtin_amdgcn_mfma_f32_16x16x32_bf16(a,b,c,0,0,0)

__device__ inline unsigned short f2bf(float f) {
  unsigned u = __builtin_bit_cast(unsigned, f);
  u += 0x7FFFu + ((u >> 16) & 1u);   // RNE
  return (unsigned short)(u >> 16);
}

// pack two f32 -> two truncated bf16 in one v_perm_b32 (P >= 0 so trunc = floor;
// <= 1 ulp (2^-8 rel) vs RNE, bias cancels in O/l). NOTE: v_cvt_pk_bf16_f32
// inline asm produced corrupt results on this toolchain (rounds 6 & 17) - do
// not reintroduce it.
__device__ inline unsigned pack_bf16_trunc(float lo, float hi) {
  return __builtin_amdgcn_perm(__builtin_bit_cast(unsigned, hi),
                               __builtin_bit_cast(unsigned, lo), 0x07060302u);
}

__device__ inline void gload_lds16(const void* g, void* l) {
  __builtin_amdgcn_global_load_lds(
      (const __attribute__((address_space(1))) void*)g,
      (__attribute__((address_space(3))) void*)l, 16, 0, 0);
}

// ---------------- fused cast fp32 -> bf16 for x,Wq,Wk,Wv,Wo ----------------
__global__ void cast_all(const float* __restrict__ x,  const float* __restrict__ wq,
                         const float* __restrict__ wk, const float* __restrict__ wv,
                         const float* __restrict__ wo, unsigned short* __restrict__ dst) {
  const int c0 = 2097152;            // x      (8388608 elems /4)
  const int c1 = c0 + 1048576;       // Wq
  const int c2 = c1 + 262144;        // Wk
  const int c3 = c2 + 262144;        // Wv
  const int c4 = c3 + 1048576;       // Wo
  int i = blockIdx.x * blockDim.x + threadIdx.x;
  const int stride = gridDim.x * blockDim.x;
  for (; i < c4; i += stride) {
    const float* src; int off;
    if      (i < c0) { src = x;  off = i; }
    else if (i < c1) { src = wq; off = i - c0; }
    else if (i < c2) { src = wk; off = i - c1; }
    else if (i < c3) { src = wv; off = i - c2; }
    else             { src = wo; off = i - c3; }
    float4 f = reinterpret_cast<const float4*>(src)[off];
    ushort4 u;
    u.x = f2bf(f.x); u.y = f2bf(f.y); u.z = f2bf(f.z); u.w = f2bf(f.w);
    reinterpret_cast<ushort4*>(dst)[i] = u;
  }
}

// ---------------- fused QKV projection GEMM: 128x192 tile, EXACT 2-blocks/CU ------
// (v15-verified) BM=128, BN=192 (virtual QKV cols 3072 = 16 x 192), BK=64.
// Grid 512 = exactly 2 per CU. 8 waves (2M x 4N), per-wave 64x48 (acc[4][3]).
// LDS dbuf: As[2][128x64] + Bs[2][192x64] = 80KB. Thin counted-vmcnt schedule.
// Q output (seg 0) is scaled by K2 = SCALE*log2(e) for log2-unit attn scores.
__global__ __launch_bounds__(512, 4) void gemm_qkv(
    const unsigned short* __restrict__ A,
    const unsigned short* __restrict__ Wq, const unsigned short* __restrict__ Wk,
    const unsigned short* __restrict__ Wv,
    const float* __restrict__ bq, const float* __restrict__ bk, const float* __restrict__ bv,
    unsigned short* __restrict__ Qo, unsigned short* __restrict__ Ko,
    unsigned short* __restrict__ Vto)
{
  __shared__ __align__(16) unsigned short As[2][8192];    // [buf][128*64]  2x16KB
  __shared__ __align__(16) unsigned short Bs[2][12288];   // [buf][192*64]  2x24KB
  const int tid  = threadIdx.x;
  const int w    = tid >> 6;
  const int lane = tid & 63;
  const int g    = blockIdx.x & 7;        // XCD slot
  const int s    = blockIdx.x >> 3;       // 0..63
  const int bm   = g*4 + (s >> 4);        // 0..31 (4 bm-panels per XCD)
  const int bn   = s & 15;                // 0..15
  const int m0   = bm << 7;
  const int n0v  = bn * 192;              // virtual col in [Q|K|V] = 3072
  const int K    = E_;
  const float K2S = 0.125f * 1.44269504088896340736f;   // SCALE * log2(e)

  const int mgrp = w >> 2;                // 0/1: rows mgrp*64
  const int ngrp = w & 3;                 // cols ngrp*48
  const int cl   = lane & 15;
  const int kgrp = lane >> 4;
  const int rl   = kgrp << 2;
  const int li   = lane >> 3;             // staging row-in-group 0..7
  const int lx   = lane & 7;              // staging chunk 0..7

  // staging bases; global chunk = lx^li (inverse swizzle)
  const unsigned gsw = ((unsigned)(lx ^ li)) << 3;   // elems
  const unsigned short* gA = A + (size_t)(m0 + w*16 + li) * K + gsw;
  const unsigned short* gBq[3];
  #pragma unroll
  for (int q = 0; q < 3; ++q) {
    const int vr = n0v + w*24 + q*8;      // seg-uniform (2048/2560 % 8 == 0)
    const unsigned short* base;
    if (vr < 2048)      base = Wq + (size_t)vr * K;
    else if (vr < 2560) base = Wk + (size_t)(vr - 2048) * K;
    else                base = Wv + (size_t)(vr - 2560) * K;
    gBq[q] = base + (size_t)li * K + gsw;
  }
  const unsigned aDst = (unsigned)(w*16)*64u + (unsigned)lane*8u;  // elems
  const unsigned bDst = (unsigned)(w*24)*64u + (unsigned)lane*8u;

  // read offsets (elems): row*64 + ((ks*4+kgrp)^(cl&7))*8
  unsigned rAo[4][2], rBo[3][2];
  #pragma unroll
  for (int ks = 0; ks < 2; ++ks) {
    const unsigned c8 = (((unsigned)(ks*4 + kgrp)) ^ (unsigned)(cl & 7)) << 3;
    #pragma unroll
    for (int z = 0; z < 4; ++z)
      rAo[z][ks] = (unsigned)(mgrp*64 + z*16 + cl) * 64u + c8;
    #pragma unroll
    for (int jj = 0; jj < 3; ++jj)
      rBo[jj][ks] = (unsigned)(ngrp*48 + jj*16 + cl) * 64u + c8;
  }

  f32x4 acc[4][3] = {};
  const int nt = K >> 6;   // 32

  auto STAGE = [&](int kt, int buf) {   // 5 wave-loads: 2 A + 3 B
    const int ko = kt << 6;
    #pragma unroll
    for (int q = 0; q < 2; ++q)
      gload_lds16(gA + (size_t)(q*8)*K + ko, &As[buf][aDst + q*512u]);
    #pragma unroll
    for (int q = 0; q < 3; ++q)
      gload_lds16(gBq[q] + ko, &Bs[buf][bDst + q*512u]);
  };

  STAGE(0, 0);
  int p = 0;

  for (int t = 0; t < nt; ++t) {
    if (t + 1 < nt) {
      STAGE(t + 1, p ^ 1);
      asm volatile("s_waitcnt vmcnt(5)" ::: "memory");   // tile-t landed
    } else {
      asm volatile("s_waitcnt vmcnt(0)" ::: "memory");
    }
    __builtin_amdgcn_s_barrier();
    #pragma unroll
    for (int ks = 0; ks < 2; ++ks) {
      bf16x8 af[4], bfr[3];
      #pragma unroll
      for (int z = 0; z < 4; ++z)
        af[z] = *reinterpret_cast<const bf16x8*>(&As[p][rAo[z][ks]]);
      #pragma unroll
      for (int jj = 0; jj < 3; ++jj)
        bfr[jj] = *reinterpret_cast<const bf16x8*>(&Bs[p][rBo[jj][ks]]);
      __builtin_amdgcn_s_setprio(1);
      #pragma unroll
      for (int z = 0; z < 4; ++z)
        #pragma unroll
        for (int jj = 0; jj < 3; ++jj)
          acc[z][jj] = MFMA16(af[z], bfr[jj], acc[z][jj]);
      __builtin_amdgcn_s_setprio(0);
    }
    __builtin_amdgcn_s_barrier();   // reads consumed -> safe to restage buf p
    p ^= 1;
  }

  // epilogue: per-(jj) 16-col fragment is segment-uniform (2048/2560 % 16 == 0)
  #pragma unroll
  for (int z = 0; z < 4; ++z) {
    const int rowb = m0 + mgrp*64 + z*16 + rl;
    #pragma unroll
    for (int jj = 0; jj < 3; ++jj) {
      const int col16 = n0v + ngrp*48 + jj*16;
      if (col16 < 2048) {
        const int col = col16 + cl;
        const float bj = bq[col];
        #pragma unroll
        for (int r = 0; r < 4; ++r)
          Qo[(size_t)(rowb + r) * 2048 + col] = f2bf((acc[z][jj][r] + bj) * K2S);
      } else if (col16 < 2560) {
        const int col = col16 - 2048 + cl;
        const float bj = bk[col];
        #pragma unroll
        for (int r = 0; r < 4; ++r)
          Ko[(size_t)(rowb + r) * 512 + col] = f2bf(acc[z][jj][r] + bj);
      } else {
        const int col = col16 - 2560 + cl;
        const float bj = bv[col];
        ushort4 u;
        u.x = f2bf(acc[z][jj][0] + bj);
        u.y = f2bf(acc[z][jj][1] + bj);
        u.z = f2bf(acc[z][jj][2] + bj);
        u.w = f2bf(acc[z][jj][3] + bj);
        *reinterpret_cast<ushort4*>(&Vto[(size_t)col * 4096 + rowb]) = u;
      }
    }
  }
}

// ---------------- out-proj GEMM: v15 engine, BM=128 BN=128 BK=64, fp32 out --------
// Port of the v15-verified thin counted-vmcnt dbuf engine. Grid 512 = exact
// 2 blocks/CU (LDS 64KB each). 512 thr = 8 waves (2M x 4N), per-wave 64x32
// (acc[4][2]). Per tile: STAGE(t+1)->buf^1 (4 wave-loads: 2 A + 2 B) ->
// vmcnt(4) -> s_barrier -> 2 ks x (6 ds_read_b128 + setprio'd 8 MFMA) ->
// s_barrier. Both-sides XOR swizzle (v15-identical index math). XCD grouping.
__global__ __launch_bounds__(512, 4) void gemm_out(
    const unsigned short* __restrict__ A, const unsigned short* __restrict__ W,
    const float* __restrict__ bias, float* __restrict__ C)
{
  __shared__ __align__(16) unsigned short As[2][8192];    // [buf][128*64]  2x16KB
  __shared__ __align__(16) unsigned short Bs[2][8192];    // [buf][128*64]  2x16KB
  const int tid  = threadIdx.x;
  const int w    = tid >> 6;
  const int lane = tid & 63;
  const int g    = blockIdx.x & 7;        // XCD slot
  const int s    = blockIdx.x >> 3;       // 0..63
  const int bm   = g*4 + (s >> 4);        // 0..31 (4 bm-panels per XCD)
  const int bn   = s & 15;                // 0..15
  const int m0   = bm << 7;
  const int n0   = bn << 7;
  const int K    = E_;

  const int mgrp = w >> 2;                // 0/1: rows mgrp*64
  const int ngrp = w & 3;                 // cols ngrp*32
  const int cl   = lane & 15;
  const int kgrp = lane >> 4;
  const int rl   = kgrp << 2;
  const int li   = lane >> 3;             // staging row-in-group 0..7
  const int lx   = lane & 7;              // staging chunk 0..7

  // staging bases; global chunk = lx^li (inverse swizzle)
  const unsigned gsw = ((unsigned)(lx ^ li)) << 3;   // elems
  const unsigned short* gA = A + (size_t)(m0 + w*16 + li) * K + gsw;
  const unsigned short* gB = W + (size_t)(n0 + w*16 + li) * K + gsw;
  const unsigned dSt = (unsigned)(w*16)*64u + (unsigned)lane*8u;   // elems

  // read offsets (elems): row*64 + ((ks*4+kgrp)^(cl&7))*8
  unsigned rAo[4][2], rBo[2][2];
  #pragma unroll
  for (int ks = 0; ks < 2; ++ks) {
    const unsigned c8 = (((unsigned)(ks*4 + kgrp)) ^ (unsigned)(cl & 7)) << 3;
    #pragma unroll
    for (int z = 0; z < 4; ++z)
      rAo[z][ks] = (unsigned)(mgrp*64 + z*16 + cl) * 64u + c8;
    #pragma unroll
    for (int jj = 0; jj < 2; ++jj)
      rBo[jj][ks] = (unsigned)(ngrp*32 + jj*16 + cl) * 64u + c8;
  }

  f32x4 acc[4][2] = {};
  const int nt = K >> 6;   // 32

  auto STAGE = [&](int kt, int buf) {   // 4 wave-loads: 2 A + 2 B
    const int ko = kt << 6;
    #pragma unroll
    for (int q = 0; q < 2; ++q)
      gload_lds16(gA + (size_t)(q*8)*K + ko, &As[buf][dSt + q*512u]);
    #pragma unroll
    for (int q = 0; q < 2; ++q)
      gload_lds16(gB + (size_t)(q*8)*K + ko, &Bs[buf][dSt + q*512u]);
  };

  STAGE(0, 0);
  int p = 0;

  for (int t = 0; t < nt; ++t) {
    if (t + 1 < nt) {
      STAGE(t + 1, p ^ 1);
      asm volatile("s_waitcnt vmcnt(4)" ::: "memory");   // tile-t landed
    } else {
      asm volatile("s_waitcnt vmcnt(0)" ::: "memory");
    }
    __builtin_amdgcn_s_barrier();
    #pragma unroll
    for (int ks = 0; ks < 2; ++ks) {
      bf16x8 af[4], bfr[2];
      #pragma unroll
      for (int z = 0; z < 4; ++z)
        af[z] = *reinterpret_cast<const bf16x8*>(&As[p][rAo[z][ks]]);
      #pragma unroll
      for (int jj = 0; jj < 2; ++jj)
        bfr[jj] = *reinterpret_cast<const bf16x8*>(&Bs[p][rBo[jj][ks]]);
      __builtin_amdgcn_s_setprio(1);
      #pragma unroll
      for (int z = 0; z < 4; ++z)
        #pragma unroll
        for (int jj = 0; jj < 2; ++jj)
          acc[z][jj] = MFMA16(af[z], bfr[jj], acc[z][jj]);
      __builtin_amdgcn_s_setprio(0);
    }
    __builtin_amdgcn_s_barrier();   // reads consumed -> safe to restage buf p
    p ^= 1;
  }

  // epilogue: fp32 + bias
  #pragma unroll
  for (int z = 0; z < 4; ++z) {
    const int rowb = m0 + mgrp*64 + z*16 + rl;
    #pragma unroll
    for (int jj = 0; jj < 2; ++jj) {
      const int col = n0 + ngrp*32 + jj*16 + cl;
      const float bj = bias[col];
      #pragma unroll
      for (int r = 0; r < 4; ++r)
        C[(size_t)(rowb + r) * E_ + col] = acc[z][jj][r] + bj;
    }
  }
}

// ---------------- causal GQA flash attention (v20: log2-unit scores) --------------
// grid (16, 64): x = bh = b*8+h (-> XCD h via %8 dispatch), y: strip index
// sidx = 63 - y (longest-first). Block = 4 waves = the 4 query heads sharing
// (b,h)'s K/V, one 32-row strip, 3 blocks/CU. Engine = v19 (verified) except:
// Q pre-scaled by K2 at projection, so exp2(s - m) directly; THR = 3.0 (log2
// units, P <= 8); max tree in max3-fusable form; v_perm P-pack; defer-max.
__global__ __launch_bounds__(256, 3) void attn_kernel(
    const unsigned short* __restrict__ Q, const unsigned short* __restrict__ K,
    const unsigned short* __restrict__ Vt, unsigned short* __restrict__ O)
{
  __shared__ __align__(16) unsigned short Kbuf[2][4096];   // [64 kv][64 d] swizzled
  __shared__ __align__(16) unsigned short Vbuf[2][4096];   // [64 d][64 kv] swizzled
  __shared__ __align__(16) unsigned short Ps[4][2048];     // per-wave P
  const int tid  = threadIdx.x;
  const int w    = tid >> 6;
  const int lane = tid & 63;
  const int bh   = blockIdx.x;      // b*8 + h
  const int b    = bh >> 3;
  const int h    = bh & 7;
  const int sidx = 63 - (int)blockIdx.y;   // strip 63..0 (longest first)
  const int hq   = h*4 + w;         // this wave's query head
  const int cl   = lane & 15;
  const int kgrp = lane >> 4;
  const int rl   = kgrp << 2;
  const int li   = lane >> 3;       // 0..7 (staging row-in-group)
  const int lx   = lane & 7;        // 0..7 (staging chunk)

  const float THR = 3.0f;           // defer-max bound (log2 units): P <= 2^3 = 8

  char* pws = (char*)&Ps[w][0];
  const unsigned swz = ((unsigned)(cl & 7)) << 4;

  bf16x8 ones8;
  #pragma unroll
  for (int q = 0; q < 8; ++q) ones8[q] = (short)0x3F80;   // bf16 1.0

  const char* Kp = (const char*)(K + (size_t)(b*N_)*512 + h*64);
  const char* Vp = (const char*)(Vt + (size_t)(h*64)*BN_ + b*N_);

  // staging constants: instr i covers rows i*8+li; global chunk = (lx^li)
  const unsigned schunk = ((unsigned)(lx ^ li)) << 4;
  const unsigned kso  = (unsigned)li*1024u + schunk;   // + i*8192  + t*65536
  const unsigned vso  = (unsigned)li*8192u + schunk;   // + i*65536 + t*128
  const unsigned ldst = (unsigned)lane*16u;            // + i*1024

  // fragment read offsets: row z*16+cl, chunk (ks*4+kgrp)^(cl&7)
  unsigned rdo[4][2];
  #pragma unroll
  for (int z = 0; z < 4; ++z)
    #pragma unroll
    for (int ks = 0; ks < 2; ++ks)
      rdo[z][ks] = (unsigned)z*2048u + (unsigned)cl*128u
                 + ((((unsigned)ks*4u + (unsigned)kgrp) ^ (unsigned)(cl & 7)) << 4);

  // P LDS offsets: write b64 (4 kv), read b128 (8 kv)
  unsigned wb[2][4], rb[2][2];
  #pragma unroll
  for (int i = 0; i < 2; ++i) {
    #pragma unroll
    for (int c = 0; c < 4; ++c)
      wb[i][c] = (unsigned)i*2048u + (unsigned)cl*128u
               + (((unsigned)c*32u + (unsigned)kgrp*8u) ^ swz);
    #pragma unroll
    for (int ks = 0; ks < 2; ++ks)
      rb[i][ks] = (unsigned)i*2048u + (unsigned)cl*128u
                + (((unsigned)ks*64u + (unsigned)kgrp*16u) ^ swz);
  }

  const int q0 = sidx << 5;
  const int nt = (sidx >> 1) + 1;   // kv tiles of 64

  // Q fragments (B-operand): lane cl = q row
  bf16x8 qf[2][2];
  #pragma unroll
  for (int i = 0; i < 2; ++i) {
    const size_t qoff = (size_t)(b*N_ + q0 + i*16 + cl) * E_ + hq*64 + (kgrp << 3);
    qf[i][0] = *reinterpret_cast<const bf16x8*>(Q + qoff);
    qf[i][1] = *reinterpret_cast<const bf16x8*>(Q + qoff + 32);
  }

  f32x4 o[2][4] = {};
  f32x4 l4[2] = {};
  float m[2] = {-1e30f, -1e30f};

  // stage tile 0 into buffer 0 (each wave: 2 K + 2 V instructions)
  #pragma unroll
  for (int q = 0; q < 2; ++q) {
    const unsigned i = (unsigned)(w*2 + q);
    gload_lds16(Kp + (i*8192u + kso),  (char*)Kbuf[0] + (i*1024u + ldst));
    gload_lds16(Vp + (i*65536u + vso), (char*)Vbuf[0] + (i*1024u + ldst));
  }
  int cur = 0;
  __syncthreads();   // drain stage

  for (int t = 0; t < nt; ++t) {
    // ---- stage tile t+1 into other buffer (overlaps with compute below) ----
    if (t + 1 < nt) {
      const unsigned kt = (unsigned)(t + 1) * 65536u;
      const unsigned vt = (unsigned)(t + 1) * 128u;
      #pragma unroll
      for (int q = 0; q < 2; ++q) {
        const unsigned i = (unsigned)(w*2 + q);
        gload_lds16(Kp + (kt + i*8192u + kso),  (char*)Kbuf[cur^1] + (i*1024u + ldst));
        gload_lds16(Vp + (vt + i*65536u + vso), (char*)Vbuf[cur^1] + (i*1024u + ldst));
      }
    }

    // ---- K fragments from LDS ----
    bf16x8 kf[4][2];
    #pragma unroll
    for (int c = 0; c < 4; ++c)
      #pragma unroll
      for (int ks = 0; ks < 2; ++ks)
        kf[c][ks] = *reinterpret_cast<const bf16x8*>((const char*)Kbuf[cur] + rdo[c][ks]);

    // ---- S^T = K Q (log2 units; Q pre-scaled by K2) ----
    f32x4 s[2][4];
    #pragma unroll
    for (int i = 0; i < 2; ++i)
      #pragma unroll
      for (int c = 0; c < 4; ++c) {
        f32x4 z = {};
        z = MFMA16(kf[c][0], qf[i][0], z);
        z = MFMA16(kf[c][1], qf[i][1], z);
        s[i][c] = z;
      }

    // ---- causal mask (last tile only): kv > q -> -inf ----
    if (t == nt - 1) {
      const int kvb = t << 6;
      #pragma unroll
      for (int i = 0; i < 2; ++i) {
        const int qq = q0 + i*16 + cl;
        #pragma unroll
        for (int c = 0; c < 4; ++c)
          #pragma unroll
          for (int r = 0; r < 4; ++r)
            if (kvb + c*16 + rl + r > qq) s[i][c][r] = -1e30f;
      }
    }

    // ---- softmax per i-block: DEFER-MAX (T13), max3 tree, v_perm P-pack ----
    #pragma unroll
    for (int i = 0; i < 2; ++i) {
      const float v0 = fmaxf(fmaxf(s[i][0][0], s[i][0][1]), s[i][0][2]);
      const float v1 = fmaxf(fmaxf(s[i][0][3], s[i][1][0]), s[i][1][1]);
      const float v2 = fmaxf(fmaxf(s[i][1][2], s[i][1][3]), s[i][2][0]);
      const float v3 = fmaxf(fmaxf(s[i][2][1], s[i][2][2]), s[i][2][3]);
      const float v4 = fmaxf(fmaxf(s[i][3][0], s[i][3][1]), s[i][3][2]);
      const float lm = fmaxf(fmaxf(fmaxf(v0, v1), v2),
                             fmaxf(fmaxf(v3, v4), s[i][3][3]));
      if (!__all(lm <= m[i] + THR)) {
        // rare path (first tile + occasional growth): exact reduce + rescale
        float tm = lm;
        tm = fmaxf(tm, __shfl_xor(tm, 16, 64));
        tm = fmaxf(tm, __shfl_xor(tm, 32, 64));
        const float mn = fmaxf(m[i], tm);
        const float al = __builtin_amdgcn_exp2f(m[i] - mn);
        m[i] = mn;
        l4[i] *= al;
        #pragma unroll
        for (int db = 0; db < 4; ++db) o[i][db] *= al;
      }
      const float mn = m[i];
      #pragma unroll
      for (int c = 0; c < 4; ++c) {
        const float e0 = __builtin_amdgcn_exp2f(s[i][c][0] - mn);
        const float e1 = __builtin_amdgcn_exp2f(s[i][c][1] - mn);
        const float e2 = __builtin_amdgcn_exp2f(s[i][c][2] - mn);
        const float e3 = __builtin_amdgcn_exp2f(s[i][c][3] - mn);
        uint2 u;
        u.x = pack_bf16_trunc(e0, e1);
        u.y = pack_bf16_trunc(e2, e3);
        *reinterpret_cast<uint2*>(pws + wb[i][c]) = u;
      }
    }

    // ---- V fragments from LDS ----
    bf16x8 vf[4][2];
    #pragma unroll
    for (int db = 0; db < 4; ++db)
      #pragma unroll
      for (int ks = 0; ks < 2; ++ks)
        vf[db][ks] = *reinterpret_cast<const bf16x8*>((const char*)Vbuf[cur] + rdo[db][ks]);

    // ---- O^T += V^T P ; l += 1 . P ----
    #pragma unroll
    for (int i = 0; i < 2; ++i) {
      const bf16x8 pa0 = *reinterpret_cast<const bf16x8*>(pws + rb[i][0]);
      const bf16x8 pa1 = *reinterpret_cast<const bf16x8*>(pws + rb[i][1]);
      l4[i] = MFMA16(ones8, pa0, l4[i]);
      l4[i] = MFMA16(ones8, pa1, l4[i]);
      #pragma unroll
      for (int db = 0; db < 4; ++db) {
        o[i][db] = MFMA16(vf[db][0], pa0, o[i][db]);
        o[i][db] = MFMA16(vf[db][1], pa1, o[i][db]);
      }
    }

    __syncthreads();   // stage(t+1) drained + all waves done reading buf[cur]
    cur ^= 1;
  }

  // ---- epilogue: O[q][hq*64 + d] = o/l (RNE f2bf, 8B stores) ----
  #pragma unroll
  for (int i = 0; i < 2; ++i) {
    const float inv = 1.0f / l4[i][0];
    const size_t orow = (size_t)(b*N_ + q0 + i*16 + cl) * E_ + hq*64 + rl;
    #pragma unroll
    for (int db = 0; db < 4; ++db) {
      ushort4 u;
      u.x = f2bf(o[i][db][0] * inv);
      u.y = f2bf(o[i][db][1] * inv);
      u.z = f2bf(o[i][db][2] * inv);
      u.w = f2bf(o[i][db][3] * inv);
      *reinterpret_cast<ushort4*>(&O[orow + db*16]) = u;
    }
  }
}

extern "C" void kernel_launch(void* const* d_in, const int* in_sizes, int n_in,
                              void* d_out, int out_size, void* d_ws, size_t ws_size,
                              hipStream_t stream) {
  const float* x  = (const float*)d_in[0];
  const float* Wq = (const float*)d_in[1];
  const float* bq = (const float*)d_in[2];
  const float* Wk = (const float*)d_in[3];
  const float* bk = (const float*)d_in[4];
  const float* Wv = (const float*)d_in[5];
  const float* bv = (const float*)d_in[6];
  const float* Wo = (const float*)d_in[7];
  const float* bo = (const float*)d_in[8];
  float* out = (float*)d_out;

  // workspace carve (bf16 elements); cast destinations contiguous in input order
  unsigned short* ws  = (unsigned short*)d_ws;
  unsigned short* xb  = ws;              // 4096x2048
  unsigned short* Wqb = xb  + 8388608;   // 2048x2048
  unsigned short* Wkb = Wqb + 4194304;   // 512x2048
  unsigned short* Wvb = Wkb + 1048576;   // 512x2048
  unsigned short* Wob = Wvb + 1048576;   // 2048x2048
  unsigned short* Qb  = Wob + 4194304;   // 4096x2048
  unsigned short* Kb  = Qb  + 8388608;   // 4096x512
  unsigned short* Vtb = Kb  + 2097152;   // 512x4096 (V transposed)
  unsigned short* Ob  = Vtb + 2097152;   // 4096x2048

  cast_all<<<dim3(2048), dim3(256), 0, stream>>>(x, Wq, Wk, Wv, Wo, xb);

  gemm_qkv<<<dim3(512), dim3(512), 0, stream>>>(xb, Wqb, Wkb, Wvb,
                                                bq, bk, bv, Qb, Kb, Vtb);

  attn_kernel<<<dim3(16, 64), dim3(256), 0, stream>>>(Qb, Kb, Vtb, Ob);

  gemm_out<<<dim3(512), dim3(512), 0, stream>>>(Ob, Wob, bo, out);
}